// Round 4
// baseline (4826.631 us; speedup 1.0000x reference)
//
#include <hip/hip_runtime.h>

// ---------------- constants ----------------
constexpr int C_B   = 4;
constexpr int C_T   = 1024;
constexpr int C_D   = 768;
constexpr int C_H   = 12;
constexpr int C_HS  = 64;
constexpr int C_FF  = 3072;
constexpr int C_V   = 32000;
constexpr int C_L   = 12;
constexpr int ROWS  = C_B * C_T;      // 4096
constexpr int QKVN  = 3 * C_D;        // 2304

typedef __bf16 bf16;
typedef __attribute__((ext_vector_type(8))) __bf16 bf16x8;
typedef __attribute__((ext_vector_type(4))) float  f32x4;

// ---------------- embedding: x = tok_emb[idx] + pos_emb (fp32 in, fp32 out) ----------------
__global__ __launch_bounds__(256) void embed_kernel(const int* __restrict__ idx,
    const float* __restrict__ tok, const float* __restrict__ pos, float* __restrict__ x) {
  int gid = blockIdx.x * 256 + threadIdx.x;     // grid covers ROWS*C_D exactly
  int row = gid / C_D, d = gid - row * C_D;
  int t = row & (C_T - 1);
  x[gid] = tok[(long)idx[row] * C_D + d] + pos[(long)t * C_D + d];
}

// ---------------- layernorm: fp32 x -> bf16 out (g,b fp32 at element offset goff) ----------------
__global__ __launch_bounds__(256) void ln_kernel(const float* __restrict__ x,
    const float* __restrict__ g, const float* __restrict__ bb, long goff,
    bf16* __restrict__ out) {
  int row = blockIdx.x, tid = threadIdx.x;
  const float* xr = x + (long)row * C_D;
  float v0 = xr[tid], v1 = xr[tid + 256], v2 = xr[tid + 512];
  float s = v0 + v1 + v2;
  float s2 = v0 * v0 + v1 * v1 + v2 * v2;
#pragma unroll
  for (int off = 32; off > 0; off >>= 1) {
    s  += __shfl_down(s, off);
    s2 += __shfl_down(s2, off);
  }
  __shared__ float sm[4], sq[4];
  if ((tid & 63) == 0) { sm[tid >> 6] = s; sq[tid >> 6] = s2; }
  __syncthreads();
  s  = sm[0] + sm[1] + sm[2] + sm[3];
  s2 = sq[0] + sq[1] + sq[2] + sq[3];
  float mean = s * (1.f / C_D);
  float var  = s2 * (1.f / C_D) - mean * mean;   // biased var, matches reference
  float rstd = rsqrtf(var + 1e-5f);
  bf16* orow = out + (long)row * C_D;
  orow[tid]       = (bf16)((v0 - mean) * rstd * g[goff + tid]       + bb[goff + tid]);
  orow[tid + 256] = (bf16)((v1 - mean) * rstd * g[goff + tid + 256] + bb[goff + tid + 256]);
  orow[tid + 512] = (bf16)((v2 - mean) * rstd * g[goff + tid + 512] + bb[goff + tid + 512]);
}

// ---------------- tiled transpose+convert: fp32 src[K][N] (+soff0) -> bf16 dst[N][K] ----------------
__global__ __launch_bounds__(256) void transpose_kernel(const float* __restrict__ src,
    bf16* __restrict__ dst, int K, int N, long soff0, long src_bstride, long dst_bstride,
    int ntn) {
  __shared__ bf16 tile[32][33];
  int bz = blockIdx.y;
  bf16* d = dst + (long)bz * dst_bstride;
  const float* s = src + soff0 + (long)bz * src_bstride;
  int tn = blockIdx.x % ntn, tk = blockIdx.x / ntn;
  int c = threadIdx.x & 31, r = threadIdx.x >> 5;
#pragma unroll
  for (int it = 0; it < 4; ++it)
    tile[r + 8 * it][c] = (bf16)s[(long)(tk * 32 + r + 8 * it) * N + tn * 32 + c];
  __syncthreads();
#pragma unroll
  for (int it = 0; it < 4; ++it)
    d[(long)(tn * 32 + r + 8 * it) * K + tk * 32 + c] = tile[c][r + 8 * it];
}

// ---------------- GEMM: C[M,N] = A[M,K] @ Bt[N,K]^T (+bias fp32 at offset boff) ----------------
// MODE 0: bf16 out = acc + bias ; MODE 1: bf16 relu ; MODE 2: fp32 resid += ; MODE 3: fp32 out
template <int MODE>
__global__ __launch_bounds__(256) void gemm_bt(const bf16* __restrict__ A,
    const bf16* __restrict__ Bt, const float* __restrict__ bias, long boff,
    void* __restrict__ outp, float* __restrict__ resid, int N, int K) {
  __shared__ __attribute__((aligned(16))) bf16 lsA[128 * 32];
  __shared__ __attribute__((aligned(16))) bf16 lsB[128 * 32];
  int tid = threadIdx.x;
  int l = tid & 63;
  int w = tid >> 6, wr = w >> 1, wc = w & 1;
  int lg = l >> 4, lr = l & 15;
  long row0 = (long)blockIdx.y * 128, col0 = (long)blockIdx.x * 128;

  const bf16* ga = A  + (row0 + (tid >> 2)) * K + (tid & 3) * 8;
  const bf16* gb = Bt + (col0 + (tid >> 2)) * K + (tid & 3) * 8;
  bf16* la = lsA + tid * 8;
  bf16* lb = lsB + tid * 8;

  f32x4 acc[4][4];
  const f32x4 fz = {0.f, 0.f, 0.f, 0.f};
#pragma unroll
  for (int m = 0; m < 4; ++m)
#pragma unroll
    for (int n = 0; n < 4; ++n) acc[m][n] = fz;

  for (int k0 = 0; k0 < K; k0 += 32) {
    bf16x8 ta0 = *(const bf16x8*)ga;
    bf16x8 ta1 = *(const bf16x8*)(ga + (long)64 * K);
    bf16x8 tb0 = *(const bf16x8*)gb;
    bf16x8 tb1 = *(const bf16x8*)(gb + (long)64 * K);
    ga += 32; gb += 32;
    *(bf16x8*)la = ta0;
    *(bf16x8*)(la + 2048) = ta1;
    *(bf16x8*)lb = tb0;
    *(bf16x8*)(lb + 2048) = tb1;
    __syncthreads();
    bf16x8 af[4], bfr[4];
#pragma unroll
    for (int m = 0; m < 4; ++m)
      af[m] = *(const bf16x8*)(lsA + (wr * 64 + m * 16 + lr) * 32 + lg * 8);
#pragma unroll
    for (int n = 0; n < 4; ++n)
      bfr[n] = *(const bf16x8*)(lsB + (wc * 64 + n * 16 + lr) * 32 + lg * 8);
#pragma unroll
    for (int m = 0; m < 4; ++m)
#pragma unroll
      for (int n = 0; n < 4; ++n)
        acc[m][n] = __builtin_amdgcn_mfma_f32_16x16x32_bf16(af[m], bfr[n], acc[m][n], 0, 0, 0);
    __syncthreads();
  }

#pragma unroll
  for (int n = 0; n < 4; ++n) {
    long gc = col0 + wc * 64 + n * 16 + lr;
    float bv = bias ? bias[boff + gc] : 0.f;
#pragma unroll
    for (int m = 0; m < 4; ++m) {
      long gr = row0 + wr * 64 + m * 16 + lg * 4;
#pragma unroll
      for (int r = 0; r < 4; ++r) {
        float v = acc[m][n][r] + bv;
        if (MODE == 2) {
          resid[(gr + r) * N + gc] += v;
        } else if (MODE == 3) {
          ((float*)outp)[(gr + r) * N + gc] = v;
        } else {
          if (MODE == 1) v = fmaxf(v, 0.f);
          ((bf16*)outp)[(gr + r) * N + gc] = (bf16)v;
        }
      }
    }
  }
}

// ---------------- flash attention: 1 wave = 16 q-rows of one (b,h) ----------------
__global__ __launch_bounds__(64) void attn_kernel(const bf16* __restrict__ qkv,
                                                  bf16* __restrict__ attout) {
  int qt = blockIdx.x & 63;
  int bh = blockIdx.x >> 6;
  int b = bh / C_H, h = bh % C_H;
  int l = threadIdx.x;
  int lg = l >> 4, lr = l & 15;
  const bf16* base = qkv + (long)b * C_T * QKVN;

  const bf16* qp = base + (long)(qt * 16 + lr) * QKVN + h * C_HS;
  bf16x8 qf0 = *(const bf16x8*)(qp + lg * 8);
  bf16x8 qf1 = *(const bf16x8*)(qp + 32 + lg * 8);

  const f32x4 fz = {0.f, 0.f, 0.f, 0.f};
  f32x4 o[4] = {fz, fz, fz, fz};
  float m_run[4], l_run[4];
#pragma unroll
  for (int r = 0; r < 4; ++r) { m_run[r] = -1e30f; l_run[r] = 0.f; }

  __shared__ __attribute__((aligned(16))) bf16 p_lds[16][40];
  __shared__ __attribute__((aligned(16))) bf16 vt_lds[64][40];

  int nkt = (qt * 16 + 15) / 32 + 1;     // 32-key tiles needed (causal)
  for (int kt = 0; kt < nkt; ++kt) {
    int key0 = kt * 32;
    f32x4 sacc[2];
#pragma unroll
    for (int ss = 0; ss < 2; ++ss) {
      const bf16* kp = base + (long)(key0 + ss * 16 + lr) * QKVN + C_D + h * C_HS;
      bf16x8 kf0 = *(const bf16x8*)(kp + lg * 8);
      bf16x8 kf1 = *(const bf16x8*)(kp + 32 + lg * 8);
      f32x4 a = fz;
      a = __builtin_amdgcn_mfma_f32_16x16x32_bf16(qf0, kf0, a, 0, 0, 0);
      a = __builtin_amdgcn_mfma_f32_16x16x32_bf16(qf1, kf1, a, 0, 0, 0);
      sacc[ss] = a;
    }
#pragma unroll
    for (int r = 0; r < 4; ++r) {
      int qrow = qt * 16 + lg * 4 + r;
      bool u0 = (key0 + lr) <= qrow;
      bool u1 = (key0 + 16 + lr) <= qrow;
      float s0 = u0 ? sacc[0][r] * 0.125f : -1e30f;
      float s1 = u1 ? sacc[1][r] * 0.125f : -1e30f;
      float mr = fmaxf(s0, s1);
      mr = fmaxf(mr, __shfl_xor(mr, 1));
      mr = fmaxf(mr, __shfl_xor(mr, 2));
      mr = fmaxf(mr, __shfl_xor(mr, 4));
      mr = fmaxf(mr, __shfl_xor(mr, 8));
      float mnew = fmaxf(m_run[r], mr);
      float scale = __expf(m_run[r] - mnew);
      float p0 = u0 ? __expf(s0 - mnew) : 0.f;
      float p1 = u1 ? __expf(s1 - mnew) : 0.f;
      float rs = p0 + p1;
      rs += __shfl_xor(rs, 1);
      rs += __shfl_xor(rs, 2);
      rs += __shfl_xor(rs, 4);
      rs += __shfl_xor(rs, 8);
      l_run[r] = l_run[r] * scale + rs;
      m_run[r] = mnew;
      o[0][r] *= scale; o[1][r] *= scale; o[2][r] *= scale; o[3][r] *= scale;
      p_lds[lg * 4 + r][lr]      = (bf16)p0;
      p_lds[lg * 4 + r][16 + lr] = (bf16)p1;
    }
#pragma unroll
    for (int it = 0; it < 4; ++it) {
      int kl = it * 8 + (l >> 3);
      int d0 = (l & 7) * 8;
      bf16x8 vv = *(const bf16x8*)(base + (long)(key0 + kl) * QKVN + 2 * C_D + h * C_HS + d0);
#pragma unroll
      for (int j = 0; j < 8; ++j) vt_lds[d0 + j][kl] = vv[j];
    }
    __syncthreads();
    bf16x8 pf = *(const bf16x8*)(&p_lds[lr][lg * 8]);
#pragma unroll
    for (int c = 0; c < 4; ++c) {
      bf16x8 vf = *(const bf16x8*)(&vt_lds[c * 16 + lr][lg * 8]);
      o[c] = __builtin_amdgcn_mfma_f32_16x16x32_bf16(pf, vf, o[c], 0, 0, 0);
    }
    __syncthreads();
  }
#pragma unroll
  for (int c = 0; c < 4; ++c)
#pragma unroll
    for (int r = 0; r < 4; ++r) {
      int qrow = qt * 16 + lg * 4 + r;
      attout[((long)b * C_T + qrow) * C_D + h * C_HS + c * 16 + lr] =
          (bf16)(o[c][r] / l_run[r]);
    }
}

// ---------------- per-row loss on fp32 logits: -log softmax[target] ----------------
__global__ __launch_bounds__(256) void loss_kernel(const float* __restrict__ logits,
    const int* __restrict__ targets, float* __restrict__ rowloss) {
  int row = blockIdx.x, tid = threadIdx.x;
  const float* lrow = logits + (long)row * C_V;
  float m = -1e30f, sum = 0.f;
  for (int i4 = tid * 4; i4 < C_V; i4 += 1024) {
    f32x4 v4 = *(const f32x4*)(lrow + i4);
#pragma unroll
    for (int j = 0; j < 4; ++j) {
      float v = v4[j];
      if (v > m) { sum *= __expf(m - v); m = v; }
      sum += __expf(v - m);
    }
  }
#pragma unroll
  for (int off = 32; off > 0; off >>= 1) {
    float mo = __shfl_down(m, off), so = __shfl_down(sum, off);
    float M = fmaxf(m, mo);
    sum = sum * __expf(m - M) + so * __expf(mo - M);
    m = M;
  }
  __shared__ float sm[4], ss[4];
  if ((tid & 63) == 0) { sm[tid >> 6] = m; ss[tid >> 6] = sum; }
  __syncthreads();
  if (tid == 0) {
    float M = sm[0], S = ss[0];
    for (int wv = 1; wv < 4; ++wv) {
      float M2 = fmaxf(M, sm[wv]);
      S = S * __expf(M - M2) + ss[wv] * __expf(sm[wv] - M2);
      M = M2;
    }
    float lt = lrow[targets[row]];
    rowloss[row] = -(lt - M - logf(S));
  }
}

__global__ __launch_bounds__(256) void loss_final(const float* __restrict__ rowloss,
                                                  float* __restrict__ out) {
  int tid = threadIdx.x;
  float s = 0.f;
  for (int i = tid; i < ROWS; i += 256) s += rowloss[i];
#pragma unroll
  for (int off = 32; off > 0; off >>= 1) s += __shfl_down(s, off);
  __shared__ float sm[4];
  if ((tid & 63) == 0) sm[tid >> 6] = s;
  __syncthreads();
  if (tid == 0) out[0] = (sm[0] + sm[1] + sm[2] + sm[3]) * (1.f / ROWS);
}

// ---------------- launch ----------------
extern "C" void kernel_launch(void* const* d_in, const int* in_sizes, int n_in,
                              void* d_out, int out_size, void* d_ws, size_t ws_size,
                              hipStream_t stream) {
  (void)in_sizes; (void)n_in; (void)out_size; (void)ws_size;
  const int*   idx     = (const int*)  d_in[0];
  const int*   targets = (const int*)  d_in[1];
  const float* tok     = (const float*)d_in[2];
  const float* pos     = (const float*)d_in[3];
  const float* Wq      = (const float*)d_in[4];
  const float* Wk      = (const float*)d_in[5];
  const float* Wv      = (const float*)d_in[6];
  const float* Wo      = (const float*)d_in[7];
  const float* bo      = (const float*)d_in[8];
  const float* W1      = (const float*)d_in[9];
  const float* b1      = (const float*)d_in[10];
  const float* W2      = (const float*)d_in[11];
  const float* b2      = (const float*)d_in[12];
  const float* ln1g    = (const float*)d_in[13];
  const float* ln1b    = (const float*)d_in[14];
  const float* ln2g    = (const float*)d_in[15];
  const float* ln2b    = (const float*)d_in[16];
  const float* lnfg    = (const float*)d_in[17];
  const float* lnfb    = (const float*)d_in[18];
  const float* Wlm     = (const float*)d_in[19];
  const float* blm     = (const float*)d_in[20];

  char* p = (char*)d_ws;
  auto alloc = [&](size_t bytes) {
    char* r = p; p += (bytes + 255) & ~(size_t)255; return r;
  };
  float* x       = (float*)alloc((size_t)ROWS * C_D * 4);
  bf16*  h       = (bf16*) alloc((size_t)ROWS * C_D * 2);
  bf16*  qkv     = (bf16*) alloc((size_t)ROWS * QKVN * 2);   // \  after the layer
  bf16*  attout  = (bf16*) alloc((size_t)ROWS * C_D * 2);    //  > loop this region
  bf16*  ffbuf   = (bf16*) alloc((size_t)ROWS * C_FF * 2);   // /  is reused as wlmt
  bf16*  wqkvt   = (bf16*) alloc((size_t)QKVN * C_D * 2);
  bf16*  wot     = (bf16*) alloc((size_t)C_D * C_D * 2);
  bf16*  w1t     = (bf16*) alloc((size_t)C_FF * C_D * 2);
  bf16*  w2t     = (bf16*) alloc((size_t)C_D * C_FF * 2);
  float* rowloss = (float*)alloc((size_t)ROWS * 4);
  bf16*  wlmt    = qkv;   // alias: 49.15 MB needed, qkv+attout+ffbuf = 50.33 MB

  float* logits = (float*)d_out;   // [ROWS][C_V] fp32, then loss at [ROWS*C_V]

  embed_kernel<<<ROWS * C_D / 256, 256, 0, stream>>>(idx, tok, pos, x);

  for (int l = 0; l < C_L; ++l) {
    long wqkv_off = (long)l * C_H * C_D * C_HS;   // element offsets into fused L-dim
    // per-head Wq/Wk/Wv [768,64] -> rows h*64..h*64+63 of wqkvt [2304,768]
    transpose_kernel<<<dim3(48, 12), 256, 0, stream>>>(
        Wq, wqkvt,                    C_D, C_HS, wqkv_off, (long)C_D * C_HS, (long)C_HS * C_D, 2);
    transpose_kernel<<<dim3(48, 12), 256, 0, stream>>>(
        Wk, wqkvt + (long)C_D * C_D,  C_D, C_HS, wqkv_off, (long)C_D * C_HS, (long)C_HS * C_D, 2);
    transpose_kernel<<<dim3(48, 12), 256, 0, stream>>>(
        Wv, wqkvt + (long)2 * C_D * C_D, C_D, C_HS, wqkv_off, (long)C_D * C_HS, (long)C_HS * C_D, 2);
    transpose_kernel<<<dim3(24 * 24, 1), 256, 0, stream>>>(
        Wo, wot, C_D, C_D, (long)l * C_D * C_D, 0, 0, 24);
    transpose_kernel<<<dim3(96 * 24, 1), 256, 0, stream>>>(
        W1, w1t, C_D, C_FF, (long)l * C_D * C_FF, 0, 0, 96);
    transpose_kernel<<<dim3(24 * 96, 1), 256, 0, stream>>>(
        W2, w2t, C_FF, C_D, (long)l * C_FF * C_D, 0, 0, 24);

    ln_kernel<<<ROWS, 256, 0, stream>>>(x, ln1g, ln1b, (long)l * C_D, h);
    gemm_bt<0><<<dim3(QKVN / 128, ROWS / 128), 256, 0, stream>>>(
        h, wqkvt, nullptr, 0, qkv, nullptr, QKVN, C_D);
    attn_kernel<<<C_B * C_H * (C_T / 16), 64, 0, stream>>>(qkv, attout);
    gemm_bt<2><<<dim3(C_D / 128, ROWS / 128), 256, 0, stream>>>(
        attout, wot, bo, (long)l * C_D, nullptr, x, C_D, C_D);
    ln_kernel<<<ROWS, 256, 0, stream>>>(x, ln2g, ln2b, (long)l * C_D, h);
    gemm_bt<1><<<dim3(C_FF / 128, ROWS / 128), 256, 0, stream>>>(
        h, w1t, b1, (long)l * C_FF, ffbuf, nullptr, C_FF, C_D);
    gemm_bt<2><<<dim3(C_D / 128, ROWS / 128), 256, 0, stream>>>(
        ffbuf, w2t, b2, (long)l * C_D, nullptr, x, C_D, C_FF);
  }

  // Wlm [768, 32000] -> wlmt [32000, 768]  (after loop: aliases dead buffers)
  transpose_kernel<<<dim3((C_V / 32) * (C_D / 32), 1), 256, 0, stream>>>(
      Wlm, wlmt, C_D, C_V, 0, 0, 0, C_V / 32);

  ln_kernel<<<ROWS, 256, 0, stream>>>(x, lnfg, lnfb, 0, h);
  gemm_bt<3><<<dim3(C_V / 128, ROWS / 128), 256, 0, stream>>>(
      h, wlmt, blm, 0, logits, nullptr, C_V, C_D);
  loss_kernel<<<ROWS, 256, 0, stream>>>(logits, targets, rowloss);
  loss_final<<<1, 256, 0, stream>>>(rowloss, logits + (long)ROWS * C_V);
}

// Round 5
// 4596.849 us; speedup vs baseline: 1.0500x; 1.0500x over previous
//
#include <hip/hip_runtime.h>

// ---------------- constants ----------------
constexpr int C_B   = 4;
constexpr int C_T   = 1024;
constexpr int C_D   = 768;
constexpr int C_H   = 12;
constexpr int C_HS  = 64;
constexpr int C_FF  = 3072;
constexpr int C_V   = 32000;
constexpr int C_L   = 12;
constexpr int ROWS  = C_B * C_T;      // 4096
constexpr int QKVN  = 3 * C_D;        // 2304

typedef __bf16 bf16;
typedef __attribute__((ext_vector_type(8))) __bf16 bf16x8;
typedef __attribute__((ext_vector_type(4))) float  f32x4;

static __device__ __forceinline__ void gload16(const void* g, void* l) {
  __builtin_amdgcn_global_load_lds((const __attribute__((address_space(1))) void*)g,
                                   (__attribute__((address_space(3))) void*)l,
                                   16, 0, 0);
}

// ---------------- embedding: x = tok_emb[idx] + pos_emb (fp32) ----------------
__global__ __launch_bounds__(256) void embed_kernel(const int* __restrict__ idx,
    const float* __restrict__ tok, const float* __restrict__ pos, float* __restrict__ x) {
  int gid = blockIdx.x * 256 + threadIdx.x;     // grid covers ROWS*C_D exactly
  int row = gid / C_D, d = gid - row * C_D;
  int t = row & (C_T - 1);
  x[gid] = tok[(long)idx[row] * C_D + d] + pos[(long)t * C_D + d];
}

// ---------------- layernorm: fp32 x -> bf16 out ----------------
__global__ __launch_bounds__(256) void ln_kernel(const float* __restrict__ x,
    const float* __restrict__ g, const float* __restrict__ bb, long goff,
    bf16* __restrict__ out) {
  int row = blockIdx.x, tid = threadIdx.x;
  const float* xr = x + (long)row * C_D;
  float v0 = xr[tid], v1 = xr[tid + 256], v2 = xr[tid + 512];
  float s = v0 + v1 + v2;
  float s2 = v0 * v0 + v1 * v1 + v2 * v2;
#pragma unroll
  for (int off = 32; off > 0; off >>= 1) {
    s  += __shfl_down(s, off);
    s2 += __shfl_down(s2, off);
  }
  __shared__ float sm[4], sq[4];
  if ((tid & 63) == 0) { sm[tid >> 6] = s; sq[tid >> 6] = s2; }
  __syncthreads();
  s  = sm[0] + sm[1] + sm[2] + sm[3];
  s2 = sq[0] + sq[1] + sq[2] + sq[3];
  float mean = s * (1.f / C_D);
  float var  = s2 * (1.f / C_D) - mean * mean;   // biased var, matches reference
  float rstd = rsqrtf(var + 1e-5f);
  bf16* orow = out + (long)row * C_D;
  orow[tid]       = (bf16)((v0 - mean) * rstd * g[goff + tid]       + bb[goff + tid]);
  orow[tid + 256] = (bf16)((v1 - mean) * rstd * g[goff + tid + 256] + bb[goff + tid + 256]);
  orow[tid + 512] = (bf16)((v2 - mean) * rstd * g[goff + tid + 512] + bb[goff + tid + 512]);
}

// ---------------- generic tiled transpose+convert (used for Wlm only) ----------------
__global__ __launch_bounds__(256) void transpose_kernel(const float* __restrict__ src,
    bf16* __restrict__ dst, int K, int N, long soff0, int ntn) {
  __shared__ bf16 tile[32][33];
  const float* s = src + soff0;
  int tn = blockIdx.x % ntn, tk = blockIdx.x / ntn;
  int c = threadIdx.x & 31, r = threadIdx.x >> 5;
#pragma unroll
  for (int it = 0; it < 4; ++it)
    tile[r + 8 * it][c] = (bf16)s[(long)(tk * 32 + r + 8 * it) * N + tn * 32 + c];
  __syncthreads();
#pragma unroll
  for (int it = 0; it < 4; ++it)
    dst[(long)(tn * 32 + r + 8 * it) * K + tk * 32 + c] = tile[c][r + 8 * it];
}

// ---------------- all per-layer weight transposes in ONE launch ----------------
// grid = 6912 blocks: [0,1728) Wq/Wk/Wv per-head, [1728,2304) Wo,
// [2304,4608) W1, [4608,6912) W2. Each block does one 32x32 tile.
__global__ __launch_bounds__(256) void transpose_layer_kernel(
    const float* __restrict__ Wq, const float* __restrict__ Wk,
    const float* __restrict__ Wv, const float* __restrict__ Wo,
    const float* __restrict__ W1, const float* __restrict__ W2,
    bf16* __restrict__ wqkvt, bf16* __restrict__ wot,
    bf16* __restrict__ w1t, bf16* __restrict__ w2t, int l) {
  int bid = blockIdx.x;
  const float* src; bf16* dst; int K, N, ntn, t;
  if (bid < 1728) {
    int which = bid / 576, r = bid % 576, head = r / 48;
    t = r % 48;
    const float* W = which == 0 ? Wq : which == 1 ? Wk : Wv;
    src = W + (long)l * C_H * C_D * C_HS + (long)head * C_D * C_HS;
    dst = wqkvt + (long)which * C_D * C_D + (long)head * C_HS * C_D;
    K = C_D; N = C_HS; ntn = 2;
  } else if (bid < 2304) {
    t = bid - 1728; src = Wo + (long)l * C_D * C_D; dst = wot;
    K = C_D; N = C_D; ntn = 24;
  } else if (bid < 4608) {
    t = bid - 2304; src = W1 + (long)l * C_D * C_FF; dst = w1t;
    K = C_D; N = C_FF; ntn = 96;
  } else {
    t = bid - 4608; src = W2 + (long)l * C_FF * C_D; dst = w2t;
    K = C_FF; N = C_D; ntn = 24;
  }
  __shared__ bf16 tile[32][33];
  int tn = t % ntn, tk = t / ntn;
  int c = threadIdx.x & 31, r = threadIdx.x >> 5;
#pragma unroll
  for (int it = 0; it < 4; ++it)
    tile[r + 8 * it][c] = (bf16)src[(long)(tk * 32 + r + 8 * it) * N + tn * 32 + c];
  __syncthreads();
#pragma unroll
  for (int it = 0; it < 4; ++it)
    dst[(long)(tn * 32 + r + 8 * it) * K + tk * 32 + c] = tile[c][r + 8 * it];
}

// ---------------- GEMM: C[M,N] = A[M,K] @ Bt[N,K]^T (+bias fp32 at offset boff) ----------------
// m97 structure: 128x128 tile, BK=32, width-16 global_load_lds staging.
// MODE 0: bf16 out = acc + bias ; MODE 1: bf16 relu ; MODE 2: fp32 resid += ; MODE 3: fp32 out
template <int MODE>
__global__ __launch_bounds__(256) void gemm_bt(const bf16* __restrict__ A,
    const bf16* __restrict__ Bt, const float* __restrict__ bias, long boff,
    void* __restrict__ outp, float* __restrict__ resid, int N, int K) {
  __shared__ __attribute__((aligned(16))) bf16 lsA[128 * 32];
  __shared__ __attribute__((aligned(16))) bf16 lsB[128 * 32];
  int tid = threadIdx.x;
  int l = tid & 63;
  int w = tid >> 6, wr = w >> 1, wc = w & 1;
  int lg = l >> 4, lr = l & 15;
  long row0 = (long)blockIdx.y * 128, col0 = (long)blockIdx.x * 128;

  const bf16* ga = A  + (row0 + (tid >> 2)) * K + (tid & 3) * 8;
  const bf16* gb = Bt + (col0 + (tid >> 2)) * K + (tid & 3) * 8;
  bf16* la = lsA + tid * 8;    // lane-linear: wave-uniform base + lane*16B
  bf16* lb = lsB + tid * 8;

  f32x4 acc[4][4];
  const f32x4 fz = {0.f, 0.f, 0.f, 0.f};
#pragma unroll
  for (int m = 0; m < 4; ++m)
#pragma unroll
    for (int n = 0; n < 4; ++n) acc[m][n] = fz;

  for (int k0 = 0; k0 < K; k0 += 32) {
    gload16(ga, la);  gload16(ga + (long)64 * K, la + 2048);
    gload16(gb, lb);  gload16(gb + (long)64 * K, lb + 2048);
    ga += 32; gb += 32;
    __syncthreads();   // compiler drains vmcnt before barrier
    bf16x8 af[4], bfr[4];
#pragma unroll
    for (int m = 0; m < 4; ++m)
      af[m] = *(const bf16x8*)(lsA + (wr * 64 + m * 16 + lr) * 32 + lg * 8);
#pragma unroll
    for (int n = 0; n < 4; ++n)
      bfr[n] = *(const bf16x8*)(lsB + (wc * 64 + n * 16 + lr) * 32 + lg * 8);
#pragma unroll
    for (int m = 0; m < 4; ++m)
#pragma unroll
      for (int n = 0; n < 4; ++n)
        acc[m][n] = __builtin_amdgcn_mfma_f32_16x16x32_bf16(af[m], bfr[n], acc[m][n], 0, 0, 0);
    __syncthreads();
  }

#pragma unroll
  for (int n = 0; n < 4; ++n) {
    long gc = col0 + wc * 64 + n * 16 + lr;
    float bv = bias ? bias[boff + gc] : 0.f;
#pragma unroll
    for (int m = 0; m < 4; ++m) {
      long gr = row0 + wr * 64 + m * 16 + lg * 4;
#pragma unroll
      for (int r = 0; r < 4; ++r) {
        float v = acc[m][n][r] + bv;
        if (MODE == 2) {
          resid[(gr + r) * N + gc] += v;
        } else if (MODE == 3) {
          ((float*)outp)[(gr + r) * N + gc] = v;
        } else {
          if (MODE == 1) v = fmaxf(v, 0.f);
          ((bf16*)outp)[(gr + r) * N + gc] = (bf16)v;
        }
      }
    }
  }
}

// ---------------- flash attention: 1 wave = 16 q-rows of one (b,h) ----------------
__global__ __launch_bounds__(64) void attn_kernel(const bf16* __restrict__ qkv,
                                                  bf16* __restrict__ attout) {
  int qt = blockIdx.x & 63;
  int bh = blockIdx.x >> 6;
  int b = bh / C_H, h = bh % C_H;
  int l = threadIdx.x;
  int lg = l >> 4, lr = l & 15;
  const bf16* base = qkv + (long)b * C_T * QKVN;

  const bf16* qp = base + (long)(qt * 16 + lr) * QKVN + h * C_HS;
  bf16x8 qf0 = *(const bf16x8*)(qp + lg * 8);
  bf16x8 qf1 = *(const bf16x8*)(qp + 32 + lg * 8);

  const f32x4 fz = {0.f, 0.f, 0.f, 0.f};
  f32x4 o[4] = {fz, fz, fz, fz};
  float m_run[4], l_run[4];
#pragma unroll
  for (int r = 0; r < 4; ++r) { m_run[r] = -1e30f; l_run[r] = 0.f; }

  __shared__ __attribute__((aligned(16))) bf16 p_lds[16][40];
  __shared__ __attribute__((aligned(16))) bf16 vt_lds[64][40];

  int nkt = (qt * 16 + 15) / 32 + 1;     // 32-key tiles needed (causal)
  for (int kt = 0; kt < nkt; ++kt) {
    int key0 = kt * 32;
    f32x4 sacc[2];
#pragma unroll
    for (int ss = 0; ss < 2; ++ss) {
      const bf16* kp = base + (long)(key0 + ss * 16 + lr) * QKVN + C_D + h * C_HS;
      bf16x8 kf0 = *(const bf16x8*)(kp + lg * 8);
      bf16x8 kf1 = *(const bf16x8*)(kp + 32 + lg * 8);
      f32x4 a = fz;
      a = __builtin_amdgcn_mfma_f32_16x16x32_bf16(qf0, kf0, a, 0, 0, 0);
      a = __builtin_amdgcn_mfma_f32_16x16x32_bf16(qf1, kf1, a, 0, 0, 0);
      sacc[ss] = a;
    }
#pragma unroll
    for (int r = 0; r < 4; ++r) {
      int qrow = qt * 16 + lg * 4 + r;
      bool u0 = (key0 + lr) <= qrow;
      bool u1 = (key0 + 16 + lr) <= qrow;
      float s0 = u0 ? sacc[0][r] * 0.125f : -1e30f;
      float s1 = u1 ? sacc[1][r] * 0.125f : -1e30f;
      float mr = fmaxf(s0, s1);
      mr = fmaxf(mr, __shfl_xor(mr, 1));
      mr = fmaxf(mr, __shfl_xor(mr, 2));
      mr = fmaxf(mr, __shfl_xor(mr, 4));
      mr = fmaxf(mr, __shfl_xor(mr, 8));
      float mnew = fmaxf(m_run[r], mr);
      float scale = __expf(m_run[r] - mnew);
      float p0 = u0 ? __expf(s0 - mnew) : 0.f;
      float p1 = u1 ? __expf(s1 - mnew) : 0.f;
      float rs = p0 + p1;
      rs += __shfl_xor(rs, 1);
      rs += __shfl_xor(rs, 2);
      rs += __shfl_xor(rs, 4);
      rs += __shfl_xor(rs, 8);
      l_run[r] = l_run[r] * scale + rs;
      m_run[r] = mnew;
      o[0][r] *= scale; o[1][r] *= scale; o[2][r] *= scale; o[3][r] *= scale;
      p_lds[lg * 4 + r][lr]      = (bf16)p0;
      p_lds[lg * 4 + r][16 + lr] = (bf16)p1;
    }
#pragma unroll
    for (int it = 0; it < 4; ++it) {
      int kl = it * 8 + (l >> 3);
      int d0 = (l & 7) * 8;
      bf16x8 vv = *(const bf16x8*)(base + (long)(key0 + kl) * QKVN + 2 * C_D + h * C_HS + d0);
#pragma unroll
      for (int j = 0; j < 8; ++j) vt_lds[d0 + j][kl] = vv[j];
    }
    __syncthreads();
    bf16x8 pf = *(const bf16x8*)(&p_lds[lr][lg * 8]);
#pragma unroll
    for (int c = 0; c < 4; ++c) {
      bf16x8 vf = *(const bf16x8*)(&vt_lds[c * 16 + lr][lg * 8]);
      o[c] = __builtin_amdgcn_mfma_f32_16x16x32_bf16(pf, vf, o[c], 0, 0, 0);
    }
    __syncthreads();
  }
#pragma unroll
  for (int c = 0; c < 4; ++c)
#pragma unroll
    for (int r = 0; r < 4; ++r) {
      int qrow = qt * 16 + lg * 4 + r;
      attout[((long)b * C_T + qrow) * C_D + h * C_HS + c * 16 + lr] =
          (bf16)(o[c][r] / l_run[r]);
    }
}

// ---------------- per-row loss on fp32 logits: -log softmax[target] ----------------
__global__ __launch_bounds__(256) void loss_kernel(const float* __restrict__ logits,
    const int* __restrict__ targets, float* __restrict__ rowloss) {
  int row = blockIdx.x, tid = threadIdx.x;
  const float* lrow = logits + (long)row * C_V;
  float m = -1e30f, sum = 0.f;
  for (int i4 = tid * 4; i4 < C_V; i4 += 1024) {
    f32x4 v4 = *(const f32x4*)(lrow + i4);
#pragma unroll
    for (int j = 0; j < 4; ++j) {
      float v = v4[j];
      if (v > m) { sum *= __expf(m - v); m = v; }
      sum += __expf(v - m);
    }
  }
#pragma unroll
  for (int off = 32; off > 0; off >>= 1) {
    float mo = __shfl_down(m, off), so = __shfl_down(sum, off);
    float M = fmaxf(m, mo);
    sum = sum * __expf(m - M) + so * __expf(mo - M);
    m = M;
  }
  __shared__ float sm[4], ss[4];
  if ((tid & 63) == 0) { sm[tid >> 6] = m; ss[tid >> 6] = sum; }
  __syncthreads();
  if (tid == 0) {
    float M = sm[0], S = ss[0];
    for (int wv = 1; wv < 4; ++wv) {
      float M2 = fmaxf(M, sm[wv]);
      S = S * __expf(M - M2) + ss[wv] * __expf(sm[wv] - M2);
      M = M2;
    }
    float lt = lrow[targets[row]];
    rowloss[row] = -(lt - M - logf(S));
  }
}

__global__ __launch_bounds__(256) void loss_final(const float* __restrict__ rowloss,
                                                  float* __restrict__ out) {
  int tid = threadIdx.x;
  float s = 0.f;
  for (int i = tid; i < ROWS; i += 256) s += rowloss[i];
#pragma unroll
  for (int off = 32; off > 0; off >>= 1) s += __shfl_down(s, off);
  __shared__ float sm[4];
  if ((tid & 63) == 0) sm[tid >> 6] = s;
  __syncthreads();
  if (tid == 0) out[0] = (sm[0] + sm[1] + sm[2] + sm[3]) * (1.f / ROWS);
}

// ---------------- launch ----------------
extern "C" void kernel_launch(void* const* d_in, const int* in_sizes, int n_in,
                              void* d_out, int out_size, void* d_ws, size_t ws_size,
                              hipStream_t stream) {
  (void)in_sizes; (void)n_in; (void)out_size; (void)ws_size;
  const int*   idx     = (const int*)  d_in[0];
  const int*   targets = (const int*)  d_in[1];
  const float* tok     = (const float*)d_in[2];
  const float* pos     = (const float*)d_in[3];
  const float* Wq      = (const float*)d_in[4];
  const float* Wk      = (const float*)d_in[5];
  const float* Wv      = (const float*)d_in[6];
  const float* Wo      = (const float*)d_in[7];
  const float* bo      = (const float*)d_in[8];
  const float* W1      = (const float*)d_in[9];
  const float* b1      = (const float*)d_in[10];
  const float* W2      = (const float*)d_in[11];
  const float* b2      = (const float*)d_in[12];
  const float* ln1g    = (const float*)d_in[13];
  const float* ln1b    = (const float*)d_in[14];
  const float* ln2g    = (const float*)d_in[15];
  const float* ln2b    = (const float*)d_in[16];
  const float* lnfg    = (const float*)d_in[17];
  const float* lnfb    = (const float*)d_in[18];
  const float* Wlm     = (const float*)d_in[19];
  const float* blm     = (const float*)d_in[20];

  char* p = (char*)d_ws;
  auto alloc = [&](size_t bytes) {
    char* r = p; p += (bytes + 255) & ~(size_t)255; return r;
  };
  float* x       = (float*)alloc((size_t)ROWS * C_D * 4);
  bf16*  h       = (bf16*) alloc((size_t)ROWS * C_D * 2);
  bf16*  qkv     = (bf16*) alloc((size_t)ROWS * QKVN * 2);   // \  after the layer
  bf16*  attout  = (bf16*) alloc((size_t)ROWS * C_D * 2);    //  > loop this region
  bf16*  ffbuf   = (bf16*) alloc((size_t)ROWS * C_FF * 2);   // /  is reused as wlmt
  bf16*  wqkvt   = (bf16*) alloc((size_t)QKVN * C_D * 2);
  bf16*  wot     = (bf16*) alloc((size_t)C_D * C_D * 2);
  bf16*  w1t     = (bf16*) alloc((size_t)C_FF * C_D * 2);
  bf16*  w2t     = (bf16*) alloc((size_t)C_D * C_FF * 2);
  float* rowloss = (float*)alloc((size_t)ROWS * 4);
  bf16*  wlmt    = qkv;   // alias: 49.15 MB needed, qkv+attout+ffbuf = 50.33 MB

  float* logits = (float*)d_out;   // [ROWS][C_V] fp32, then loss at [ROWS*C_V]

  embed_kernel<<<ROWS * C_D / 256, 256, 0, stream>>>(idx, tok, pos, x);

  for (int l = 0; l < C_L; ++l) {
    transpose_layer_kernel<<<6912, 256, 0, stream>>>(
        Wq, Wk, Wv, Wo, W1, W2, wqkvt, wot, w1t, w2t, l);

    ln_kernel<<<ROWS, 256, 0, stream>>>(x, ln1g, ln1b, (long)l * C_D, h);
    gemm_bt<0><<<dim3(QKVN / 128, ROWS / 128), 256, 0, stream>>>(
        h, wqkvt, nullptr, 0, qkv, nullptr, QKVN, C_D);
    attn_kernel<<<C_B * C_H * (C_T / 16), 64, 0, stream>>>(qkv, attout);
    gemm_bt<2><<<dim3(C_D / 128, ROWS / 128), 256, 0, stream>>>(
        attout, wot, bo, (long)l * C_D, nullptr, x, C_D, C_D);
    ln_kernel<<<ROWS, 256, 0, stream>>>(x, ln2g, ln2b, (long)l * C_D, h);
    gemm_bt<1><<<dim3(C_FF / 128, ROWS / 128), 256, 0, stream>>>(
        h, w1t, b1, (long)l * C_FF, ffbuf, nullptr, C_FF, C_D);
    gemm_bt<2><<<dim3(C_D / 128, ROWS / 128), 256, 0, stream>>>(
        ffbuf, w2t, b2, (long)l * C_D, nullptr, x, C_D, C_FF);
  }

  // Wlm [768, 32000] -> wlmt [32000, 768]  (after loop: aliases dead buffers)
  transpose_kernel<<<(C_V / 32) * (C_D / 32), 256, 0, stream>>>(
      Wlm, wlmt, C_D, C_V, 0, C_V / 32);

  ln_kernel<<<ROWS, 256, 0, stream>>>(x, lnfg, lnfb, 0, h);
  gemm_bt<3><<<dim3(C_V / 128, ROWS / 128), 256, 0, stream>>>(
      h, wlmt, blm, 0, logits, nullptr, C_V, C_D);
  loss_kernel<<<ROWS, 256, 0, stream>>>(logits, targets, rowloss);
  loss_final<<<1, 256, 0, stream>>>(rowloss, logits + (long)ROWS * C_V);
}

// Round 6
// 3720.746 us; speedup vs baseline: 1.2972x; 1.2355x over previous
//
#include <hip/hip_runtime.h>

// ---------------- constants ----------------
constexpr int C_B   = 4;
constexpr int C_T   = 1024;
constexpr int C_D   = 768;
constexpr int C_H   = 12;
constexpr int C_HS  = 64;
constexpr int C_FF  = 3072;
constexpr int C_V   = 32000;
constexpr int C_L   = 12;
constexpr int ROWS  = C_B * C_T;      // 4096
constexpr int QKVN  = 3 * C_D;        // 2304

typedef __bf16 bf16;
typedef __attribute__((ext_vector_type(8))) __bf16 bf16x8;
typedef __attribute__((ext_vector_type(4))) float  f32x4;
typedef __attribute__((ext_vector_type(4))) short  s16x4;

static __device__ __forceinline__ void gload16(const void* g, void* l) {
  __builtin_amdgcn_global_load_lds((const __attribute__((address_space(1))) void*)g,
                                   (__attribute__((address_space(3))) void*)l,
                                   16, 0, 0);
}

// ---------------- embedding: x = tok_emb[idx] + pos_emb (fp32) ----------------
__global__ __launch_bounds__(256) void embed_kernel(const int* __restrict__ idx,
    const float* __restrict__ tok, const float* __restrict__ pos, float* __restrict__ x) {
  int gid = blockIdx.x * 256 + threadIdx.x;     // grid covers ROWS*C_D exactly
  int row = gid / C_D, d = gid - row * C_D;
  int t = row & (C_T - 1);
  x[gid] = tok[(long)idx[row] * C_D + d] + pos[(long)t * C_D + d];
}

// ---------------- layernorm: fp32 x -> bf16 out ----------------
__global__ __launch_bounds__(256) void ln_kernel(const float* __restrict__ x,
    const float* __restrict__ g, const float* __restrict__ bb, long goff,
    bf16* __restrict__ out) {
  int row = blockIdx.x, tid = threadIdx.x;
  const float* xr = x + (long)row * C_D;
  float v0 = xr[tid], v1 = xr[tid + 256], v2 = xr[tid + 512];
  float s = v0 + v1 + v2;
  float s2 = v0 * v0 + v1 * v1 + v2 * v2;
#pragma unroll
  for (int off = 32; off > 0; off >>= 1) {
    s  += __shfl_down(s, off);
    s2 += __shfl_down(s2, off);
  }
  __shared__ float sm[4], sq[4];
  if ((tid & 63) == 0) { sm[tid >> 6] = s; sq[tid >> 6] = s2; }
  __syncthreads();
  s  = sm[0] + sm[1] + sm[2] + sm[3];
  s2 = sq[0] + sq[1] + sq[2] + sq[3];
  float mean = s * (1.f / C_D);
  float var  = s2 * (1.f / C_D) - mean * mean;   // biased var, matches reference
  float rstd = rsqrtf(var + 1e-5f);
  bf16* orow = out + (long)row * C_D;
  orow[tid]       = (bf16)((v0 - mean) * rstd * g[goff + tid]       + bb[goff + tid]);
  orow[tid + 256] = (bf16)((v1 - mean) * rstd * g[goff + tid + 256] + bb[goff + tid + 256]);
  orow[tid + 512] = (bf16)((v2 - mean) * rstd * g[goff + tid + 512] + bb[goff + tid + 512]);
}

// ---------------- generic tiled transpose+convert (used for Wlm only) ----------------
__global__ __launch_bounds__(256) void transpose_kernel(const float* __restrict__ src,
    bf16* __restrict__ dst, int K, int N, long soff0, int ntn) {
  __shared__ bf16 tile[32][33];
  const float* s = src + soff0;
  int tn = blockIdx.x % ntn, tk = blockIdx.x / ntn;
  int c = threadIdx.x & 31, r = threadIdx.x >> 5;
#pragma unroll
  for (int it = 0; it < 4; ++it)
    tile[r + 8 * it][c] = (bf16)s[(long)(tk * 32 + r + 8 * it) * N + tn * 32 + c];
  __syncthreads();
#pragma unroll
  for (int it = 0; it < 4; ++it)
    dst[(long)(tn * 32 + r + 8 * it) * K + tk * 32 + c] = tile[c][r + 8 * it];
}

// ---------------- all per-layer weight transposes in ONE launch ----------------
__global__ __launch_bounds__(256) void transpose_layer_kernel(
    const float* __restrict__ Wq, const float* __restrict__ Wk,
    const float* __restrict__ Wv, const float* __restrict__ Wo,
    const float* __restrict__ W1, const float* __restrict__ W2,
    bf16* __restrict__ wqkvt, bf16* __restrict__ wot,
    bf16* __restrict__ w1t, bf16* __restrict__ w2t, int l) {
  int bid = blockIdx.x;
  const float* src; bf16* dst; int K, N, ntn, t;
  if (bid < 1728) {
    int which = bid / 576, r = bid % 576, head = r / 48;
    t = r % 48;
    const float* W = which == 0 ? Wq : which == 1 ? Wk : Wv;
    src = W + (long)l * C_H * C_D * C_HS + (long)head * C_D * C_HS;
    dst = wqkvt + (long)which * C_D * C_D + (long)head * C_HS * C_D;
    K = C_D; N = C_HS; ntn = 2;
  } else if (bid < 2304) {
    t = bid - 1728; src = Wo + (long)l * C_D * C_D; dst = wot;
    K = C_D; N = C_D; ntn = 24;
  } else if (bid < 4608) {
    t = bid - 2304; src = W1 + (long)l * C_D * C_FF; dst = w1t;
    K = C_D; N = C_FF; ntn = 96;
  } else {
    t = bid - 4608; src = W2 + (long)l * C_FF * C_D; dst = w2t;
    K = C_FF; N = C_D; ntn = 24;
  }
  __shared__ bf16 tile[32][33];
  int tn = t % ntn, tk = t / ntn;
  int c = threadIdx.x & 31, r = threadIdx.x >> 5;
#pragma unroll
  for (int it = 0; it < 4; ++it)
    tile[r + 8 * it][c] = (bf16)src[(long)(tk * 32 + r + 8 * it) * N + tn * 32 + c];
  __syncthreads();
#pragma unroll
  for (int it = 0; it < 4; ++it)
    dst[(long)(tn * 32 + r + 8 * it) * K + tk * 32 + c] = tile[c][r + 8 * it];
}

// ---------------- GEMM: C[M,N] = A[M,K] @ Bt[N,K]^T (+bias fp32 at offset boff) ----------------
// 1-D grid, col-major linearization + XCD-chunked swizzle: 32 consecutive ids
// share one B-panel and land on one XCD -> B fetched ~once from HBM.
// MODE 0: bf16 out = acc + bias ; MODE 1: bf16 relu ; MODE 2: fp32 resid += ; MODE 3: fp32 out
template <int MODE>
__global__ __launch_bounds__(256) void gemm_bt(const bf16* __restrict__ A,
    const bf16* __restrict__ Bt, const float* __restrict__ bias, long boff,
    void* __restrict__ outp, float* __restrict__ resid, int N, int K) {
  __shared__ __attribute__((aligned(16))) bf16 lsA[128 * 32];
  __shared__ __attribute__((aligned(16))) bf16 lsB[128 * 32];
  int tid = threadIdx.x;
  int l = tid & 63;
  int w = tid >> 6, wr = w >> 1, wc = w & 1;
  int lg = l >> 4, lr = l & 15;

  // XCD swizzle (nwg always % 8 == 0 here); ROWS/128 == 32 row-blocks.
  int nwg = gridDim.x;
  int fid = blockIdx.x;
  int swz = (fid & 7) * (nwg >> 3) + (fid >> 3);
  long row0 = (long)(swz & 31) * 128;     // consecutive swz -> same col, next row
  long col0 = (long)(swz >> 5) * 128;

  const bf16* ga = A  + (row0 + (tid >> 2)) * K + (tid & 3) * 8;
  const bf16* gb = Bt + (col0 + (tid >> 2)) * K + (tid & 3) * 8;
  bf16* la = lsA + tid * 8;    // lane-linear: wave-uniform base + lane*16B
  bf16* lb = lsB + tid * 8;

  f32x4 acc[4][4];
  const f32x4 fz = {0.f, 0.f, 0.f, 0.f};
#pragma unroll
  for (int m = 0; m < 4; ++m)
#pragma unroll
    for (int n = 0; n < 4; ++n) acc[m][n] = fz;

  for (int k0 = 0; k0 < K; k0 += 32) {
    gload16(ga, la);  gload16(ga + (long)64 * K, la + 2048);
    gload16(gb, lb);  gload16(gb + (long)64 * K, lb + 2048);
    ga += 32; gb += 32;
    __syncthreads();
    bf16x8 af[4], bfr[4];
#pragma unroll
    for (int m = 0; m < 4; ++m)
      af[m] = *(const bf16x8*)(lsA + (wr * 64 + m * 16 + lr) * 32 + lg * 8);
#pragma unroll
    for (int n = 0; n < 4; ++n)
      bfr[n] = *(const bf16x8*)(lsB + (wc * 64 + n * 16 + lr) * 32 + lg * 8);
#pragma unroll
    for (int m = 0; m < 4; ++m)
#pragma unroll
      for (int n = 0; n < 4; ++n)
        acc[m][n] = __builtin_amdgcn_mfma_f32_16x16x32_bf16(af[m], bfr[n], acc[m][n], 0, 0, 0);
    __syncthreads();
  }

#pragma unroll
  for (int n = 0; n < 4; ++n) {
    long gc = col0 + wc * 64 + n * 16 + lr;
    float bv = bias ? bias[boff + gc] : 0.f;
#pragma unroll
    for (int m = 0; m < 4; ++m) {
      long gr = row0 + wr * 64 + m * 16 + lg * 4;
#pragma unroll
      for (int r = 0; r < 4; ++r) {
        float v = acc[m][n][r] + bv;
        if (MODE == 2) {
          resid[(gr + r) * N + gc] += v;
        } else if (MODE == 3) {
          ((float*)outp)[(gr + r) * N + gc] = v;
        } else {
          if (MODE == 1) v = fmaxf(v, 0.f);
          ((bf16*)outp)[(gr + r) * N + gc] = (bf16)v;
        }
      }
    }
  }
}

// ---------------- flash attention: 1 wave = 16 q-rows of one (b,h) ----------------
// V staged in [4k][16d]-subtiled LDS (vector writes); PV B-fragments via
// ds_read_b64_tr_b16 (HW transpose read, T10). Subtile (s=k>>2, c=d>>4) at
// byte c*1024 + (s&1)*512 + (s>>1)*128; tr-read vaddr = base + lane*8.
#define TRRD(D, OFF) asm volatile("ds_read_b64_tr_b16 %0, %1 offset:" OFF \
                                  : "=v"(D) : "v"(trp))
__global__ __launch_bounds__(64) void attn_kernel(const bf16* __restrict__ qkv,
                                                  bf16* __restrict__ attout) {
  int fid = blockIdx.x;                       // 3072 blocks, %8==0
  int swzb = (fid & 7) * 384 + (fid >> 3);    // XCD chunk: 6 (b,h) per chunk
  int qt = swzb & 63;
  int bh = swzb >> 6;
  int b = bh / C_H, h = bh % C_H;
  int l = threadIdx.x;
  int lg = l >> 4, lr = l & 15;
  const bf16* base = qkv + (long)b * C_T * QKVN;

  const bf16* qp = base + (long)(qt * 16 + lr) * QKVN + h * C_HS;
  bf16x8 qf0 = *(const bf16x8*)(qp + lg * 8);
  bf16x8 qf1 = *(const bf16x8*)(qp + 32 + lg * 8);

  const f32x4 fz = {0.f, 0.f, 0.f, 0.f};
  f32x4 o[4] = {fz, fz, fz, fz};
  float m_run[4], l_run[4];
#pragma unroll
  for (int r = 0; r < 4; ++r) { m_run[r] = -1e30f; l_run[r] = 0.f; }

  __shared__ __attribute__((aligned(16))) bf16 p_lds[16][40];
  __shared__ __attribute__((aligned(16))) bf16 vt_sub[2048];   // 4096 B subtiled

  unsigned trp = (unsigned)(unsigned long)
      ((const __attribute__((address_space(3))) char*)vt_sub + l * 8);

  int nkt = (qt * 16 + 15) / 32 + 1;     // 32-key tiles needed (causal)
  for (int kt = 0; kt < nkt; ++kt) {
    int key0 = kt * 32;
    f32x4 sacc[2];
#pragma unroll
    for (int ss = 0; ss < 2; ++ss) {
      const bf16* kp = base + (long)(key0 + ss * 16 + lr) * QKVN + C_D + h * C_HS;
      bf16x8 kf0 = *(const bf16x8*)(kp + lg * 8);
      bf16x8 kf1 = *(const bf16x8*)(kp + 32 + lg * 8);
      f32x4 a = fz;
      a = __builtin_amdgcn_mfma_f32_16x16x32_bf16(qf0, kf0, a, 0, 0, 0);
      a = __builtin_amdgcn_mfma_f32_16x16x32_bf16(qf1, kf1, a, 0, 0, 0);
      sacc[ss] = a;
    }
#pragma unroll
    for (int r = 0; r < 4; ++r) {
      int qrow = qt * 16 + lg * 4 + r;
      bool u0 = (key0 + lr) <= qrow;
      bool u1 = (key0 + 16 + lr) <= qrow;
      float s0 = u0 ? sacc[0][r] * 0.125f : -1e30f;
      float s1 = u1 ? sacc[1][r] * 0.125f : -1e30f;
      float mr = fmaxf(s0, s1);
      mr = fmaxf(mr, __shfl_xor(mr, 1));
      mr = fmaxf(mr, __shfl_xor(mr, 2));
      mr = fmaxf(mr, __shfl_xor(mr, 4));
      mr = fmaxf(mr, __shfl_xor(mr, 8));
      float mnew = fmaxf(m_run[r], mr);
      float scale = __expf(m_run[r] - mnew);
      float p0 = u0 ? __expf(s0 - mnew) : 0.f;
      float p1 = u1 ? __expf(s1 - mnew) : 0.f;
      float rs = p0 + p1;
      rs += __shfl_xor(rs, 1);
      rs += __shfl_xor(rs, 2);
      rs += __shfl_xor(rs, 4);
      rs += __shfl_xor(rs, 8);
      l_run[r] = l_run[r] * scale + rs;
      m_run[r] = mnew;
      o[0][r] *= scale; o[1][r] *= scale; o[2][r] *= scale; o[3][r] *= scale;
      p_lds[lg * 4 + r][lr]      = (bf16)p0;
      p_lds[lg * 4 + r][16 + lr] = (bf16)p1;
    }
    // ---- stage V tile into subtiled layout (4 x ds_write_b128 per lane) ----
#pragma unroll
    for (int it = 0; it < 4; ++it) {
      int kl = it * 8 + (l >> 3);
      int d0 = (l & 7) * 8;
      bf16x8 vv = *(const bf16x8*)(base + (long)(key0 + kl) * QKVN + 2 * C_D + h * C_HS + d0);
      int ba = ((d0 >> 4) << 10) + (((kl >> 2) & 1) << 9) + ((kl >> 3) << 7)
             + ((kl & 3) << 5) + ((d0 & 15) << 1);
      *(bf16x8*)((char*)vt_sub + ba) = vv;
    }
    __syncthreads();
    // ---- O += P @ V via HW transpose reads ----
    s16x4 t0a, t0b, t1a, t1b, t2a, t2b, t3a, t3b;
    TRRD(t0a, "0");    TRRD(t0b, "512");
    TRRD(t1a, "1024"); TRRD(t1b, "1536");
    TRRD(t2a, "2048"); TRRD(t2b, "2560");
    TRRD(t3a, "3072"); TRRD(t3b, "3584");
    bf16x8 pf = *(const bf16x8*)(&p_lds[lr][lg * 8]);
    asm volatile("s_waitcnt lgkmcnt(0)" ::: "memory");
    __builtin_amdgcn_sched_barrier(0);
    union uu { short s[8]; bf16x8 v; };
    auto mk = [](s16x4 a, s16x4 bq) {
      uu u;
      u.s[0] = a[0]; u.s[1] = a[1]; u.s[2] = a[2]; u.s[3] = a[3];
      u.s[4] = bq[0]; u.s[5] = bq[1]; u.s[6] = bq[2]; u.s[7] = bq[3];
      return u.v;
    };
    o[0] = __builtin_amdgcn_mfma_f32_16x16x32_bf16(pf, mk(t0a, t0b), o[0], 0, 0, 0);
    o[1] = __builtin_amdgcn_mfma_f32_16x16x32_bf16(pf, mk(t1a, t1b), o[1], 0, 0, 0);
    o[2] = __builtin_amdgcn_mfma_f32_16x16x32_bf16(pf, mk(t2a, t2b), o[2], 0, 0, 0);
    o[3] = __builtin_amdgcn_mfma_f32_16x16x32_bf16(pf, mk(t3a, t3b), o[3], 0, 0, 0);
    __syncthreads();
  }
#pragma unroll
  for (int c = 0; c < 4; ++c)
#pragma unroll
    for (int r = 0; r < 4; ++r) {
      int qrow = qt * 16 + lg * 4 + r;
      attout[((long)b * C_T + qrow) * C_D + h * C_HS + c * 16 + lr] =
          (bf16)(o[c][r] / l_run[r]);
    }
}

// ---------------- per-row loss on fp32 logits: -log softmax[target] ----------------
__global__ __launch_bounds__(256) void loss_kernel(const float* __restrict__ logits,
    const int* __restrict__ targets, float* __restrict__ rowloss) {
  int row = blockIdx.x, tid = threadIdx.x;
  const float* lrow = logits + (long)row * C_V;
  float m = -1e30f, sum = 0.f;
  for (int i4 = tid * 4; i4 < C_V; i4 += 1024) {
    f32x4 v4 = *(const f32x4*)(lrow + i4);
#pragma unroll
    for (int j = 0; j < 4; ++j) {
      float v = v4[j];
      if (v > m) { sum *= __expf(m - v); m = v; }
      sum += __expf(v - m);
    }
  }
#pragma unroll
  for (int off = 32; off > 0; off >>= 1) {
    float mo = __shfl_down(m, off), so = __shfl_down(sum, off);
    float M = fmaxf(m, mo);
    sum = sum * __expf(m - M) + so * __expf(mo - M);
    m = M;
  }
  __shared__ float sm[4], ss[4];
  if ((tid & 63) == 0) { sm[tid >> 6] = m; ss[tid >> 6] = sum; }
  __syncthreads();
  if (tid == 0) {
    float M = sm[0], S = ss[0];
    for (int wv = 1; wv < 4; ++wv) {
      float M2 = fmaxf(M, sm[wv]);
      S = S * __expf(M - M2) + ss[wv] * __expf(sm[wv] - M2);
      M = M2;
    }
    float lt = lrow[targets[row]];
    rowloss[row] = -(lt - M - logf(S));
  }
}

__global__ __launch_bounds__(256) void loss_final(const float* __restrict__ rowloss,
                                                  float* __restrict__ out) {
  int tid = threadIdx.x;
  float s = 0.f;
  for (int i = tid; i < ROWS; i += 256) s += rowloss[i];
#pragma unroll
  for (int off = 32; off > 0; off >>= 1) s += __shfl_down(s, off);
  __shared__ float sm[4];
  if ((tid & 63) == 0) sm[tid >> 6] = s;
  __syncthreads();
  if (tid == 0) out[0] = (sm[0] + sm[1] + sm[2] + sm[3]) * (1.f / ROWS);
}

// ---------------- launch ----------------
extern "C" void kernel_launch(void* const* d_in, const int* in_sizes, int n_in,
                              void* d_out, int out_size, void* d_ws, size_t ws_size,
                              hipStream_t stream) {
  (void)in_sizes; (void)n_in; (void)out_size; (void)ws_size;
  const int*   idx     = (const int*)  d_in[0];
  const int*   targets = (const int*)  d_in[1];
  const float* tok     = (const float*)d_in[2];
  const float* pos     = (const float*)d_in[3];
  const float* Wq      = (const float*)d_in[4];
  const float* Wk      = (const float*)d_in[5];
  const float* Wv      = (const float*)d_in[6];
  const float* Wo      = (const float*)d_in[7];
  const float* bo      = (const float*)d_in[8];
  const float* W1      = (const float*)d_in[9];
  const float* b1      = (const float*)d_in[10];
  const float* W2      = (const float*)d_in[11];
  const float* b2      = (const float*)d_in[12];
  const float* ln1g    = (const float*)d_in[13];
  const float* ln1b    = (const float*)d_in[14];
  const float* ln2g    = (const float*)d_in[15];
  const float* ln2b    = (const float*)d_in[16];
  const float* lnfg    = (const float*)d_in[17];
  const float* lnfb    = (const float*)d_in[18];
  const float* Wlm     = (const float*)d_in[19];
  const float* blm     = (const float*)d_in[20];

  char* p = (char*)d_ws;
  auto alloc = [&](size_t bytes) {
    char* r = p; p += (bytes + 255) & ~(size_t)255; return r;
  };
  float* x       = (float*)alloc((size_t)ROWS * C_D * 4);
  bf16*  h       = (bf16*) alloc((size_t)ROWS * C_D * 2);
  bf16*  qkv     = (bf16*) alloc((size_t)ROWS * QKVN * 2);   // \  after the layer
  bf16*  attout  = (bf16*) alloc((size_t)ROWS * C_D * 2);    //  > loop this region
  bf16*  ffbuf   = (bf16*) alloc((size_t)ROWS * C_FF * 2);   // /  is reused as wlmt
  bf16*  wqkvt   = (bf16*) alloc((size_t)QKVN * C_D * 2);
  bf16*  wot     = (bf16*) alloc((size_t)C_D * C_D * 2);
  bf16*  w1t     = (bf16*) alloc((size_t)C_FF * C_D * 2);
  bf16*  w2t     = (bf16*) alloc((size_t)C_D * C_FF * 2);
  float* rowloss = (float*)alloc((size_t)ROWS * 4);
  bf16*  wlmt    = qkv;   // alias: 49.15 MB needed, qkv+attout+ffbuf = 50.33 MB

  float* logits = (float*)d_out;   // [ROWS][C_V] fp32, then loss at [ROWS*C_V]

  embed_kernel<<<ROWS * C_D / 256, 256, 0, stream>>>(idx, tok, pos, x);

  for (int l = 0; l < C_L; ++l) {
    transpose_layer_kernel<<<6912, 256, 0, stream>>>(
        Wq, Wk, Wv, Wo, W1, W2, wqkvt, wot, w1t, w2t, l);

    ln_kernel<<<ROWS, 256, 0, stream>>>(x, ln1g, ln1b, (long)l * C_D, h);
    gemm_bt<0><<<(QKVN / 128) * 32, 256, 0, stream>>>(
        h, wqkvt, nullptr, 0, qkv, nullptr, QKVN, C_D);
    attn_kernel<<<C_B * C_H * (C_T / 16), 64, 0, stream>>>(qkv, attout);
    gemm_bt<2><<<(C_D / 128) * 32, 256, 0, stream>>>(
        attout, wot, bo, (long)l * C_D, nullptr, x, C_D, C_D);
    ln_kernel<<<ROWS, 256, 0, stream>>>(x, ln2g, ln2b, (long)l * C_D, h);
    gemm_bt<1><<<(C_FF / 128) * 32, 256, 0, stream>>>(
        h, w1t, b1, (long)l * C_FF, ffbuf, nullptr, C_FF, C_D);
    gemm_bt<2><<<(C_D / 128) * 32, 256, 0, stream>>>(
        ffbuf, w2t, b2, (long)l * C_D, nullptr, x, C_D, C_FF);
  }

  // Wlm [768, 32000] -> wlmt [32000, 768]  (after loop: aliases dead buffers)
  transpose_kernel<<<(C_V / 32) * (C_D / 32), 256, 0, stream>>>(
      Wlm, wlmt, C_D, C_V, 0, C_V / 32);

  ln_kernel<<<ROWS, 256, 0, stream>>>(x, lnfg, lnfb, 0, h);
  gemm_bt<3><<<(C_V / 128) * 32, 256, 0, stream>>>(
      h, wlmt, blm, 0, logits, nullptr, C_V, C_D);
  loss_kernel<<<ROWS, 256, 0, stream>>>(logits, targets, rowloss);
  loss_final<<<1, 256, 0, stream>>>(rowloss, logits + (long)ROWS * C_V);
}

// Round 7
// 3078.814 us; speedup vs baseline: 1.5677x; 1.2085x over previous
//
#include <hip/hip_runtime.h>

// ---------------- constants ----------------
constexpr int C_B   = 4;
constexpr int C_T   = 1024;
constexpr int C_D   = 768;
constexpr int C_H   = 12;
constexpr int C_HS  = 64;
constexpr int C_FF  = 3072;
constexpr int C_V   = 32000;
constexpr int C_L   = 12;
constexpr int ROWS  = C_B * C_T;      // 4096
constexpr int QKVN  = 3 * C_D;        // 2304

typedef __bf16 bf16;
typedef __attribute__((ext_vector_type(8))) __bf16 bf16x8;
typedef __attribute__((ext_vector_type(4))) float  f32x4;
typedef __attribute__((ext_vector_type(4))) short  s16x4;

static __device__ __forceinline__ void gload16(const void* g, void* l) {
  __builtin_amdgcn_global_load_lds((const __attribute__((address_space(1))) void*)g,
                                   (__attribute__((address_space(3))) void*)l,
                                   16, 0, 0);
}

// ---------------- embedding: x = tok_emb[idx] + pos_emb (fp32) ----------------
__global__ __launch_bounds__(256) void embed_kernel(const int* __restrict__ idx,
    const float* __restrict__ tok, const float* __restrict__ pos, float* __restrict__ x) {
  int gid = blockIdx.x * 256 + threadIdx.x;     // grid covers ROWS*C_D exactly
  int row = gid / C_D, d = gid - row * C_D;
  int t = row & (C_T - 1);
  x[gid] = tok[(long)idx[row] * C_D + d] + pos[(long)t * C_D + d];
}

// ---------------- layernorm: fp32 x -> bf16 out ----------------
__global__ __launch_bounds__(256) void ln_kernel(const float* __restrict__ x,
    const float* __restrict__ g, const float* __restrict__ bb, long goff,
    bf16* __restrict__ out) {
  int row = blockIdx.x, tid = threadIdx.x;
  const float* xr = x + (long)row * C_D;
  float v0 = xr[tid], v1 = xr[tid + 256], v2 = xr[tid + 512];
  float s = v0 + v1 + v2;
  float s2 = v0 * v0 + v1 * v1 + v2 * v2;
#pragma unroll
  for (int off = 32; off > 0; off >>= 1) {
    s  += __shfl_down(s, off);
    s2 += __shfl_down(s2, off);
  }
  __shared__ float sm[4], sq[4];
  if ((tid & 63) == 0) { sm[tid >> 6] = s; sq[tid >> 6] = s2; }
  __syncthreads();
  s  = sm[0] + sm[1] + sm[2] + sm[3];
  s2 = sq[0] + sq[1] + sq[2] + sq[3];
  float mean = s * (1.f / C_D);
  float var  = s2 * (1.f / C_D) - mean * mean;   // biased var, matches reference
  float rstd = rsqrtf(var + 1e-5f);
  bf16* orow = out + (long)row * C_D;
  orow[tid]       = (bf16)((v0 - mean) * rstd * g[goff + tid]       + bb[goff + tid]);
  orow[tid + 256] = (bf16)((v1 - mean) * rstd * g[goff + tid + 256] + bb[goff + tid + 256]);
  orow[tid + 512] = (bf16)((v2 - mean) * rstd * g[goff + tid + 512] + bb[goff + tid + 512]);
}

// ---------------- generic tiled transpose+convert (used for Wlm only) ----------------
__global__ __launch_bounds__(256) void transpose_kernel(const float* __restrict__ src,
    bf16* __restrict__ dst, int K, int N, long soff0, int ntn) {
  __shared__ bf16 tile[32][33];
  const float* s = src + soff0;
  int tn = blockIdx.x % ntn, tk = blockIdx.x / ntn;
  int c = threadIdx.x & 31, r = threadIdx.x >> 5;
#pragma unroll
  for (int it = 0; it < 4; ++it)
    tile[r + 8 * it][c] = (bf16)s[(long)(tk * 32 + r + 8 * it) * N + tn * 32 + c];
  __syncthreads();
#pragma unroll
  for (int it = 0; it < 4; ++it)
    dst[(long)(tn * 32 + r + 8 * it) * K + tk * 32 + c] = tile[c][r + 8 * it];
}

// ---------------- all per-layer weight transposes in ONE launch ----------------
__global__ __launch_bounds__(256) void transpose_layer_kernel(
    const float* __restrict__ Wq, const float* __restrict__ Wk,
    const float* __restrict__ Wv, const float* __restrict__ Wo,
    const float* __restrict__ W1, const float* __restrict__ W2,
    bf16* __restrict__ wqkvt, bf16* __restrict__ wot,
    bf16* __restrict__ w1t, bf16* __restrict__ w2t, int l) {
  int bid = blockIdx.x;
  const float* src; bf16* dst; int K, N, ntn, t;
  if (bid < 1728) {
    int which = bid / 576, r = bid % 576, head = r / 48;
    t = r % 48;
    const float* W = which == 0 ? Wq : which == 1 ? Wk : Wv;
    src = W + (long)l * C_H * C_D * C_HS + (long)head * C_D * C_HS;
    dst = wqkvt + (long)which * C_D * C_D + (long)head * C_HS * C_D;
    K = C_D; N = C_HS; ntn = 2;
  } else if (bid < 2304) {
    t = bid - 1728; src = Wo + (long)l * C_D * C_D; dst = wot;
    K = C_D; N = C_D; ntn = 24;
  } else if (bid < 4608) {
    t = bid - 2304; src = W1 + (long)l * C_D * C_FF; dst = w1t;
    K = C_D; N = C_FF; ntn = 96;
  } else {
    t = bid - 4608; src = W2 + (long)l * C_FF * C_D; dst = w2t;
    K = C_FF; N = C_D; ntn = 24;
  }
  __shared__ bf16 tile[32][33];
  int tn = t % ntn, tk = t / ntn;
  int c = threadIdx.x & 31, r = threadIdx.x >> 5;
#pragma unroll
  for (int it = 0; it < 4; ++it)
    tile[r + 8 * it][c] = (bf16)src[(long)(tk * 32 + r + 8 * it) * N + tn * 32 + c];
  __syncthreads();
#pragma unroll
  for (int it = 0; it < 4; ++it)
    dst[(long)(tn * 32 + r + 8 * it) * K + tk * 32 + c] = tile[c][r + 8 * it];
}

// ---------------- GEMM: C[M,N] = A[M,K] @ Bt[N,K]^T (+bias fp32 at offset boff) ----------------
// 2-phase double-buffered prefetch (one barrier per K-step) + full-line epilogue
// via LDS repack. 1-D grid, col-major + XCD-chunked swizzle.
// MODE 0: bf16 out = acc + bias ; MODE 1: bf16 relu ; MODE 2: fp32 resid += ; MODE 3: fp32 out
template <int MODE>
__global__ __launch_bounds__(256) void gemm_bt(const bf16* __restrict__ A,
    const bf16* __restrict__ Bt, const float* __restrict__ bias, long boff,
    void* __restrict__ outp, float* __restrict__ resid, int N, int K) {
  __shared__ __attribute__((aligned(16))) char smem[32768];   // 2 bufs x (A 8K | B 8K); reused for C
  int tid = threadIdx.x;
  int l = tid & 63;
  int w = tid >> 6, wr = w >> 1, wc = w & 1;
  int lg = l >> 4, lr = l & 15;

  int nwg = gridDim.x;
  int fid = blockIdx.x;
  int swz = (fid & 7) * (nwg >> 3) + (fid >> 3);
  long row0 = (long)(swz & 31) * 128;     // consecutive swz -> same col-panel
  long col0 = (long)(swz >> 5) * 128;

  const bf16* ga = A  + (row0 + (tid >> 2)) * K + (tid & 3) * 8;
  const bf16* gb = Bt + (col0 + (tid >> 2)) * K + (tid & 3) * 8;

  f32x4 acc[4][4];
  const f32x4 fz = {0.f, 0.f, 0.f, 0.f};
#pragma unroll
  for (int m = 0; m < 4; ++m)
#pragma unroll
    for (int n = 0; n < 4; ++n) acc[m][n] = fz;

  int nk = K >> 5;
  {   // prologue: stage buf 0
    bf16* la = (bf16*)smem + tid * 8;
    bf16* lb = (bf16*)(smem + 8192) + tid * 8;
    gload16(ga, la);  gload16(ga + (long)64 * K, la + 2048);
    gload16(gb, lb);  gload16(gb + (long)64 * K, lb + 2048);
    ga += 32; gb += 32;
  }
  int cur = 0;
  for (int t = 0; t < nk; ++t) {
    __syncthreads();                       // buf[cur] staged (drains vmcnt)
    if (t + 1 < nk) {                      // issue next-tile loads; latency hides under MFMA
      char* bufb = smem + (cur ^ 1) * 16384;
      bf16* la = (bf16*)bufb + tid * 8;
      bf16* lb = (bf16*)(bufb + 8192) + tid * 8;
      gload16(ga, la);  gload16(ga + (long)64 * K, la + 2048);
      gload16(gb, lb);  gload16(gb + (long)64 * K, lb + 2048);
      ga += 32; gb += 32;
    }
    const bf16* cA = (const bf16*)(smem + cur * 16384);
    const bf16* cB = (const bf16*)(smem + cur * 16384 + 8192);
    bf16x8 af[4], bfr[4];
#pragma unroll
    for (int m = 0; m < 4; ++m)
      af[m] = *(const bf16x8*)(cA + (wr * 64 + m * 16 + lr) * 32 + lg * 8);
#pragma unroll
    for (int n = 0; n < 4; ++n)
      bfr[n] = *(const bf16x8*)(cB + (wc * 64 + n * 16 + lr) * 32 + lg * 8);
#pragma unroll
    for (int m = 0; m < 4; ++m)
#pragma unroll
      for (int n = 0; n < 4; ++n)
        acc[m][n] = __builtin_amdgcn_mfma_f32_16x16x32_bf16(af[m], bfr[n], acc[m][n], 0, 0, 0);
    cur ^= 1;
  }
  __syncthreads();   // done with staging buffers; reuse smem for C repack

  if (MODE == 0 || MODE == 1) {
    // ---- bf16 out: full 128x128 tile staged as bf16 (32 KB), then 1KB/wave stores ----
    bf16* lc = (bf16*)smem;
#pragma unroll
    for (int n = 0; n < 4; ++n) {
      int gcl = wc * 64 + n * 16 + lr;
      float bv = bias ? bias[boff + col0 + gcl] : 0.f;
#pragma unroll
      for (int m = 0; m < 4; ++m) {
        int rb = wr * 64 + m * 16 + lg * 4;
#pragma unroll
        for (int r = 0; r < 4; ++r) {
          float v = acc[m][n][r] + bv;
          if (MODE == 1) v = fmaxf(v, 0.f);
          lc[(rb + r) * 128 + gcl] = (bf16)v;
        }
      }
    }
    __syncthreads();
#pragma unroll
    for (int it = 0; it < 8; ++it) {
      int byte = it * 4096 + tid * 16;
      int rl = byte >> 8;                 // 256 B per LDS row
      int cb = byte & 255;
      bf16x8 v = *(const bf16x8*)(smem + byte);
      *(bf16x8*)((bf16*)outp + (row0 + rl) * N + col0 + (cb >> 1)) = v;
    }
  } else {
    // ---- fp32 out: two passes of 64 rows (32 KB each) ----
#pragma unroll
    for (int pair = 0; pair < 2; ++pair) {
      float* lcf = (float*)smem;
#pragma unroll
      for (int n = 0; n < 4; ++n) {
        int gcl = wc * 64 + n * 16 + lr;
        float bv = bias ? bias[boff + col0 + gcl] : 0.f;
#pragma unroll
        for (int mi = 0; mi < 2; ++mi) {
          int m = pair * 2 + mi;
          int rl = wr * 32 + mi * 16 + lg * 4;
#pragma unroll
          for (int r = 0; r < 4; ++r)
            lcf[(rl + r) * 128 + gcl] = acc[m][n][r] + bv;
        }
      }
      __syncthreads();
#pragma unroll
      for (int it = 0; it < 8; ++it) {
        int byte = it * 4096 + tid * 16;
        int rl = byte >> 9;               // 512 B per LDS row
        int cb = byte & 511;
        long gr = row0 + (rl >> 5) * 64 + pair * 32 + ((rl >> 4) & 1) * 16 + (rl & 15);
        f32x4 v = *(const f32x4*)(smem + byte);
        if (MODE == 2) {
          f32x4 g = *(const f32x4*)(resid + gr * N + col0 + (cb >> 2));
          v += g;
          *(f32x4*)(resid + gr * N + col0 + (cb >> 2)) = v;
        } else {
          *(f32x4*)((float*)outp + gr * N + col0 + (cb >> 2)) = v;
        }
      }
      __syncthreads();
    }
  }
}

// ---------------- flash attention: 1 wave = 16 q-rows of one (b,h) ----------------
#define TRRD(D, OFF) asm volatile("ds_read_b64_tr_b16 %0, %1 offset:" OFF \
                                  : "=v"(D) : "v"(trp))
__global__ __launch_bounds__(64) void attn_kernel(const bf16* __restrict__ qkv,
                                                  bf16* __restrict__ attout) {
  int fid = blockIdx.x;                       // 3072 blocks, %8==0
  int swzb = (fid & 7) * 384 + (fid >> 3);    // XCD chunk: 6 (b,h) per chunk
  int qt = swzb & 63;
  int bh = swzb >> 6;
  int b = bh / C_H, h = bh % C_H;
  int l = threadIdx.x;
  int lg = l >> 4, lr = l & 15;
  const bf16* base = qkv + (long)b * C_T * QKVN;

  const bf16* qp = base + (long)(qt * 16 + lr) * QKVN + h * C_HS;
  bf16x8 qf0 = *(const bf16x8*)(qp + lg * 8);
  bf16x8 qf1 = *(const bf16x8*)(qp + 32 + lg * 8);

  const f32x4 fz = {0.f, 0.f, 0.f, 0.f};
  f32x4 o[4] = {fz, fz, fz, fz};
  float m_run[4], l_run[4];
#pragma unroll
  for (int r = 0; r < 4; ++r) { m_run[r] = -1e30f; l_run[r] = 0.f; }

  __shared__ __attribute__((aligned(16))) bf16 p_lds[16][40];
  __shared__ __attribute__((aligned(16))) bf16 vt_sub[2048];   // 4096 B subtiled

  unsigned trp = (unsigned)(unsigned long)
      ((const __attribute__((address_space(3))) char*)vt_sub + l * 8);

  int nkt = (qt * 16 + 15) / 32 + 1;     // 32-key tiles needed (causal)
  for (int kt = 0; kt < nkt; ++kt) {
    int key0 = kt * 32;
    f32x4 sacc[2];
#pragma unroll
    for (int ss = 0; ss < 2; ++ss) {
      const bf16* kp = base + (long)(key0 + ss * 16 + lr) * QKVN + C_D + h * C_HS;
      bf16x8 kf0 = *(const bf16x8*)(kp + lg * 8);
      bf16x8 kf1 = *(const bf16x8*)(kp + 32 + lg * 8);
      f32x4 a = fz;
      a = __builtin_amdgcn_mfma_f32_16x16x32_bf16(qf0, kf0, a, 0, 0, 0);
      a = __builtin_amdgcn_mfma_f32_16x16x32_bf16(qf1, kf1, a, 0, 0, 0);
      sacc[ss] = a;
    }
#pragma unroll
    for (int r = 0; r < 4; ++r) {
      int qrow = qt * 16 + lg * 4 + r;
      bool u0 = (key0 + lr) <= qrow;
      bool u1 = (key0 + 16 + lr) <= qrow;
      float s0 = u0 ? sacc[0][r] * 0.125f : -1e30f;
      float s1 = u1 ? sacc[1][r] * 0.125f : -1e30f;
      float mr = fmaxf(s0, s1);
      mr = fmaxf(mr, __shfl_xor(mr, 1));
      mr = fmaxf(mr, __shfl_xor(mr, 2));
      mr = fmaxf(mr, __shfl_xor(mr, 4));
      mr = fmaxf(mr, __shfl_xor(mr, 8));
      float mnew = fmaxf(m_run[r], mr);
      float scale = __expf(m_run[r] - mnew);
      float p0 = u0 ? __expf(s0 - mnew) : 0.f;
      float p1 = u1 ? __expf(s1 - mnew) : 0.f;
      float rs = p0 + p1;
      rs += __shfl_xor(rs, 1);
      rs += __shfl_xor(rs, 2);
      rs += __shfl_xor(rs, 4);
      rs += __shfl_xor(rs, 8);
      l_run[r] = l_run[r] * scale + rs;
      m_run[r] = mnew;
      o[0][r] *= scale; o[1][r] *= scale; o[2][r] *= scale; o[3][r] *= scale;
      p_lds[lg * 4 + r][lr]      = (bf16)p0;
      p_lds[lg * 4 + r][16 + lr] = (bf16)p1;
    }
    // ---- stage V tile into subtiled layout (4 x ds_write_b128 per lane) ----
#pragma unroll
    for (int it = 0; it < 4; ++it) {
      int kl = it * 8 + (l >> 3);
      int d0 = (l & 7) * 8;
      bf16x8 vv = *(const bf16x8*)(base + (long)(key0 + kl) * QKVN + 2 * C_D + h * C_HS + d0);
      int ba = ((d0 >> 4) << 10) + (((kl >> 2) & 1) << 9) + ((kl >> 3) << 7)
             + ((kl & 3) << 5) + ((d0 & 15) << 1);
      *(bf16x8*)((char*)vt_sub + ba) = vv;
    }
    __syncthreads();
    // ---- O += P @ V via HW transpose reads ----
    s16x4 t0a, t0b, t1a, t1b, t2a, t2b, t3a, t3b;
    TRRD(t0a, "0");    TRRD(t0b, "512");
    TRRD(t1a, "1024"); TRRD(t1b, "1536");
    TRRD(t2a, "2048"); TRRD(t2b, "2560");
    TRRD(t3a, "3072"); TRRD(t3b, "3584");
    bf16x8 pf = *(const bf16x8*)(&p_lds[lr][lg * 8]);
    asm volatile("s_waitcnt lgkmcnt(0)" ::: "memory");
    __builtin_amdgcn_sched_barrier(0);
    union uu { short s[8]; bf16x8 v; };
    auto mk = [](s16x4 a, s16x4 bq) {
      uu u;
      u.s[0] = a[0]; u.s[1] = a[1]; u.s[2] = a[2]; u.s[3] = a[3];
      u.s[4] = bq[0]; u.s[5] = bq[1]; u.s[6] = bq[2]; u.s[7] = bq[3];
      return u.v;
    };
    o[0] = __builtin_amdgcn_mfma_f32_16x16x32_bf16(pf, mk(t0a, t0b), o[0], 0, 0, 0);
    o[1] = __builtin_amdgcn_mfma_f32_16x16x32_bf16(pf, mk(t1a, t1b), o[1], 0, 0, 0);
    o[2] = __builtin_amdgcn_mfma_f32_16x16x32_bf16(pf, mk(t2a, t2b), o[2], 0, 0, 0);
    o[3] = __builtin_amdgcn_mfma_f32_16x16x32_bf16(pf, mk(t3a, t3b), o[3], 0, 0, 0);
    __syncthreads();
  }
#pragma unroll
  for (int c = 0; c < 4; ++c)
#pragma unroll
    for (int r = 0; r < 4; ++r) {
      int qrow = qt * 16 + lg * 4 + r;
      attout[((long)b * C_T + qrow) * C_D + h * C_HS + c * 16 + lr] =
          (bf16)(o[c][r] / l_run[r]);
    }
}

// ---------------- per-row loss on fp32 logits: -log softmax[target] ----------------
__global__ __launch_bounds__(256) void loss_kernel(const float* __restrict__ logits,
    const int* __restrict__ targets, float* __restrict__ rowloss) {
  int row = blockIdx.x, tid = threadIdx.x;
  const float* lrow = logits + (long)row * C_V;
  float m = -1e30f, sum = 0.f;
  for (int i4 = tid * 4; i4 < C_V; i4 += 1024) {
    f32x4 v4 = *(const f32x4*)(lrow + i4);
#pragma unroll
    for (int j = 0; j < 4; ++j) {
      float v = v4[j];
      if (v > m) { sum *= __expf(m - v); m = v; }
      sum += __expf(v - m);
    }
  }
#pragma unroll
  for (int off = 32; off > 0; off >>= 1) {
    float mo = __shfl_down(m, off), so = __shfl_down(sum, off);
    float M = fmaxf(m, mo);
    sum = sum * __expf(m - M) + so * __expf(mo - M);
    m = M;
  }
  __shared__ float sm[4], ss[4];
  if ((tid & 63) == 0) { sm[tid >> 6] = m; ss[tid >> 6] = sum; }
  __syncthreads();
  if (tid == 0) {
    float M = sm[0], S = ss[0];
    for (int wv = 1; wv < 4; ++wv) {
      float M2 = fmaxf(M, sm[wv]);
      S = S * __expf(M - M2) + ss[wv] * __expf(sm[wv] - M2);
      M = M2;
    }
    float lt = lrow[targets[row]];
    rowloss[row] = -(lt - M - logf(S));
  }
}

__global__ __launch_bounds__(256) void loss_final(const float* __restrict__ rowloss,
                                                  float* __restrict__ out) {
  int tid = threadIdx.x;
  float s = 0.f;
  for (int i = tid; i < ROWS; i += 256) s += rowloss[i];
#pragma unroll
  for (int off = 32; off > 0; off >>= 1) s += __shfl_down(s, off);
  __shared__ float sm[4];
  if ((tid & 63) == 0) sm[tid >> 6] = s;
  __syncthreads();
  if (tid == 0) out[0] = (sm[0] + sm[1] + sm[2] + sm[3]) * (1.f / ROWS);
}

// ---------------- launch ----------------
extern "C" void kernel_launch(void* const* d_in, const int* in_sizes, int n_in,
                              void* d_out, int out_size, void* d_ws, size_t ws_size,
                              hipStream_t stream) {
  (void)in_sizes; (void)n_in; (void)out_size; (void)ws_size;
  const int*   idx     = (const int*)  d_in[0];
  const int*   targets = (const int*)  d_in[1];
  const float* tok     = (const float*)d_in[2];
  const float* pos     = (const float*)d_in[3];
  const float* Wq      = (const float*)d_in[4];
  const float* Wk      = (const float*)d_in[5];
  const float* Wv      = (const float*)d_in[6];
  const float* Wo      = (const float*)d_in[7];
  const float* bo      = (const float*)d_in[8];
  const float* W1      = (const float*)d_in[9];
  const float* b1      = (const float*)d_in[10];
  const float* W2      = (const float*)d_in[11];
  const float* b2      = (const float*)d_in[12];
  const float* ln1g    = (const float*)d_in[13];
  const float* ln1b    = (const float*)d_in[14];
  const float* ln2g    = (const float*)d_in[15];
  const float* ln2b    = (const float*)d_in[16];
  const float* lnfg    = (const float*)d_in[17];
  const float* lnfb    = (const float*)d_in[18];
  const float* Wlm     = (const float*)d_in[19];
  const float* blm     = (const float*)d_in[20];

  char* p = (char*)d_ws;
  auto alloc = [&](size_t bytes) {
    char* r = p; p += (bytes + 255) & ~(size_t)255; return r;
  };
  float* x       = (float*)alloc((size_t)ROWS * C_D * 4);
  bf16*  h       = (bf16*) alloc((size_t)ROWS * C_D * 2);
  bf16*  qkv     = (bf16*) alloc((size_t)ROWS * QKVN * 2);   // \  after the layer
  bf16*  attout  = (bf16*) alloc((size_t)ROWS * C_D * 2);    //  > loop this region
  bf16*  ffbuf   = (bf16*) alloc((size_t)ROWS * C_FF * 2);   // /  is reused as wlmt
  bf16*  wqkvt   = (bf16*) alloc((size_t)QKVN * C_D * 2);
  bf16*  wot     = (bf16*) alloc((size_t)C_D * C_D * 2);
  bf16*  w1t     = (bf16*) alloc((size_t)C_FF * C_D * 2);
  bf16*  w2t     = (bf16*) alloc((size_t)C_D * C_FF * 2);
  float* rowloss = (float*)alloc((size_t)ROWS * 4);
  bf16*  wlmt    = qkv;   // alias: 49.15 MB needed, qkv+attout+ffbuf = 50.33 MB

  float* logits = (float*)d_out;   // [ROWS][C_V] fp32, then loss at [ROWS*C_V]

  embed_kernel<<<ROWS * C_D / 256, 256, 0, stream>>>(idx, tok, pos, x);

  for (int l = 0; l < C_L; ++l) {
    transpose_layer_kernel<<<6912, 256, 0, stream>>>(
        Wq, Wk, Wv, Wo, W1, W2, wqkvt, wot, w1t, w2t, l);

    ln_kernel<<<ROWS, 256, 0, stream>>>(x, ln1g, ln1b, (long)l * C_D, h);
    gemm_bt<0><<<(QKVN / 128) * 32, 256, 0, stream>>>(
        h, wqkvt, nullptr, 0, qkv, nullptr, QKVN, C_D);
    attn_kernel<<<C_B * C_H * (C_T / 16), 64, 0, stream>>>(qkv, attout);
    gemm_bt<2><<<(C_D / 128) * 32, 256, 0, stream>>>(
        attout, wot, bo, (long)l * C_D, nullptr, x, C_D, C_D);
    ln_kernel<<<ROWS, 256, 0, stream>>>(x, ln2g, ln2b, (long)l * C_D, h);
    gemm_bt<1><<<(C_FF / 128) * 32, 256, 0, stream>>>(
        h, w1t, b1, (long)l * C_FF, ffbuf, nullptr, C_FF, C_D);
    gemm_bt<2><<<(C_D / 128) * 32, 256, 0, stream>>>(
        ffbuf, w2t, b2, (long)l * C_D, nullptr, x, C_D, C_FF);
  }

  // Wlm [768, 32000] -> wlmt [32000, 768]  (after loop: aliases dead buffers)
  transpose_kernel<<<(C_V / 32) * (C_D / 32), 256, 0, stream>>>(
      Wlm, wlmt, C_D, C_V, 0, C_V / 32);

  ln_kernel<<<ROWS, 256, 0, stream>>>(x, lnfg, lnfb, 0, h);
  gemm_bt<3><<<(C_V / 128) * 32, 256, 0, stream>>>(
      h, wlmt, blm, 0, logits, nullptr, C_V, C_D);
  loss_kernel<<<ROWS, 256, 0, stream>>>(logits, targets, rowloss);
  loss_final<<<1, 256, 0, stream>>>(rowloss, logits + (long)ROWS * C_V);
}

// Round 8
// 3070.589 us; speedup vs baseline: 1.5719x; 1.0027x over previous
//
#include <hip/hip_runtime.h>

// ---------------- constants ----------------
constexpr int C_B   = 4;
constexpr int C_T   = 1024;
constexpr int C_D   = 768;
constexpr int C_H   = 12;
constexpr int C_HS  = 64;
constexpr int C_FF  = 3072;
constexpr int C_V   = 32000;
constexpr int C_L   = 12;
constexpr int ROWS  = C_B * C_T;      // 4096
constexpr int QKVN  = 3 * C_D;        // 2304

typedef __bf16 bf16;
typedef __attribute__((ext_vector_type(8))) __bf16 bf16x8;
typedef __attribute__((ext_vector_type(4))) float  f32x4;
typedef __attribute__((ext_vector_type(4))) short  s16x4;

static __device__ __forceinline__ void gload16(const void* g, void* l) {
  __builtin_amdgcn_global_load_lds((const __attribute__((address_space(1))) void*)g,
                                   (__attribute__((address_space(3))) void*)l,
                                   16, 0, 0);
}

// ---------------- embedding ----------------
__global__ __launch_bounds__(256) void embed_kernel(const int* __restrict__ idx,
    const float* __restrict__ tok, const float* __restrict__ pos, float* __restrict__ x) {
  int gid = blockIdx.x * 256 + threadIdx.x;
  int row = gid / C_D, d = gid - row * C_D;
  int t = row & (C_T - 1);
  x[gid] = tok[(long)idx[row] * C_D + d] + pos[(long)t * C_D + d];
}

// ---------------- layernorm ----------------
__global__ __launch_bounds__(256) void ln_kernel(const float* __restrict__ x,
    const float* __restrict__ g, const float* __restrict__ bb, long goff,
    bf16* __restrict__ out) {
  int row = blockIdx.x, tid = threadIdx.x;
  const float* xr = x + (long)row * C_D;
  float v0 = xr[tid], v1 = xr[tid + 256], v2 = xr[tid + 512];
  float s = v0 + v1 + v2;
  float s2 = v0 * v0 + v1 * v1 + v2 * v2;
#pragma unroll
  for (int off = 32; off > 0; off >>= 1) {
    s  += __shfl_down(s, off);
    s2 += __shfl_down(s2, off);
  }
  __shared__ float sm[4], sq[4];
  if ((tid & 63) == 0) { sm[tid >> 6] = s; sq[tid >> 6] = s2; }
  __syncthreads();
  s  = sm[0] + sm[1] + sm[2] + sm[3];
  s2 = sq[0] + sq[1] + sq[2] + sq[3];
  float mean = s * (1.f / C_D);
  float var  = s2 * (1.f / C_D) - mean * mean;
  float rstd = rsqrtf(var + 1e-5f);
  bf16* orow = out + (long)row * C_D;
  orow[tid]       = (bf16)((v0 - mean) * rstd * g[goff + tid]       + bb[goff + tid]);
  orow[tid + 256] = (bf16)((v1 - mean) * rstd * g[goff + tid + 256] + bb[goff + tid + 256]);
  orow[tid + 512] = (bf16)((v2 - mean) * rstd * g[goff + tid + 512] + bb[goff + tid + 512]);
}

// ---------------- generic tiled transpose+convert (Wlm) ----------------
__global__ __launch_bounds__(256) void transpose_kernel(const float* __restrict__ src,
    bf16* __restrict__ dst, int K, int N, long soff0, int ntn) {
  __shared__ bf16 tile[32][33];
  const float* s = src + soff0;
  int tn = blockIdx.x % ntn, tk = blockIdx.x / ntn;
  int c = threadIdx.x & 31, r = threadIdx.x >> 5;
#pragma unroll
  for (int it = 0; it < 4; ++it)
    tile[r + 8 * it][c] = (bf16)s[(long)(tk * 32 + r + 8 * it) * N + tn * 32 + c];
  __syncthreads();
#pragma unroll
  for (int it = 0; it < 4; ++it)
    dst[(long)(tn * 32 + r + 8 * it) * K + tk * 32 + c] = tile[c][r + 8 * it];
}

// ---------------- per-layer weight transposes, one launch ----------------
__global__ __launch_bounds__(256) void transpose_layer_kernel(
    const float* __restrict__ Wq, const float* __restrict__ Wk,
    const float* __restrict__ Wv, const float* __restrict__ Wo,
    const float* __restrict__ W1, const float* __restrict__ W2,
    bf16* __restrict__ wqkvt, bf16* __restrict__ wot,
    bf16* __restrict__ w1t, bf16* __restrict__ w2t, int l) {
  int bid = blockIdx.x;
  const float* src; bf16* dst; int K, N, ntn, t;
  if (bid < 1728) {
    int which = bid / 576, r = bid % 576, head = r / 48;
    t = r % 48;
    const float* W = which == 0 ? Wq : which == 1 ? Wk : Wv;
    src = W + (long)l * C_H * C_D * C_HS + (long)head * C_D * C_HS;
    dst = wqkvt + (long)which * C_D * C_D + (long)head * C_HS * C_D;
    K = C_D; N = C_HS; ntn = 2;
  } else if (bid < 2304) {
    t = bid - 1728; src = Wo + (long)l * C_D * C_D; dst = wot;
    K = C_D; N = C_D; ntn = 24;
  } else if (bid < 4608) {
    t = bid - 2304; src = W1 + (long)l * C_D * C_FF; dst = w1t;
    K = C_D; N = C_FF; ntn = 96;
  } else {
    t = bid - 4608; src = W2 + (long)l * C_FF * C_D; dst = w2t;
    K = C_FF; N = C_D; ntn = 24;
  }
  __shared__ bf16 tile[32][33];
  int tn = t % ntn, tk = t / ntn;
  int c = threadIdx.x & 31, r = threadIdx.x >> 5;
#pragma unroll
  for (int it = 0; it < 4; ++it)
    tile[r + 8 * it][c] = (bf16)src[(long)(tk * 32 + r + 8 * it) * N + tn * 32 + c];
  __syncthreads();
#pragma unroll
  for (int it = 0; it < 4; ++it)
    dst[(long)(tn * 32 + r + 8 * it) * K + tk * 32 + c] = tile[c][r + 8 * it];
}

// ================= 256x256 BK=64 8-wave GEMM (big-N GEMMs) =================
// LDS per buffer: A-half0|A-half1|B-half0|B-half1, 16 KB each; double buffered
// = 128 KB. Each 16 KB half-tile holds 128 rows x 64 cols bf16 in st_16x32
// subtiled layout: byte(r,c) = ((r>>4)*2+(c>>5))*1024 + (r&15)*64
//                              + (((c&31)*2) ^ ((r&8)<<2)).
// global_load_lds writes LINEAR; the global SOURCE address is pre-permuted
// (rule #21). Reads apply the same map.
// MODE 0: bf16 out (+opt bias); MODE 1: bf16 relu+bias; MODE 3: fp32 out+bias.
template <int MODE>
__global__ __launch_bounds__(512) void gemm256(const bf16* __restrict__ A,
    const bf16* __restrict__ Bt, const float* __restrict__ bias, long boff,
    void* __restrict__ outp, int N, int K) {
  __shared__ __attribute__((aligned(16))) char smem[131072];
  int tid = threadIdx.x;
  int l = tid & 63, w = tid >> 6;
  int wm = w >> 2, wn = w & 3;
  int lg = l >> 4, lr = l & 15;

  int nwg = gridDim.x;
  int fid = blockIdx.x;
  int swz = (fid & 7) * (nwg >> 3) + (fid >> 3);
  long row0 = (long)(swz & 15) * 256;      // M=4096 -> 16 row-blocks
  long col0 = (long)(swz >> 4) * 256;

  // staging address decode: linear LDS byte Y -> (R,C) element of half-tile
  int Y0 = tid * 16, Y1 = 8192 + tid * 16;
  auto dec = [](int Y, int& R, int& C) {
    int s = Y >> 10, y = Y & 1023;
    int r15 = y >> 6, z = y & 63;
    int q = (z ^ ((r15 & 8) << 2)) >> 4;
    R = (s >> 1) * 16 + r15;
    C = (s & 1) * 32 + q * 8;
  };
  int R0, C0, R1, C1;
  dec(Y0, R0, C0);  dec(Y1, R1, C1);
  const bf16* Ab = A  + row0 * K;
  const bf16* Bb = Bt + col0 * K;

  auto stage = [&](int d, int kt) {
    char* bb = smem + d * 65536;
    long kc = (long)kt * 64;
    gload16(Ab + (long)R0 * K + kc + C0, bb + Y0);
    gload16(Ab + (long)R1 * K + kc + C1, bb + Y1);
    gload16(Ab + (long)(128 + R0) * K + kc + C0, bb + 16384 + Y0);
    gload16(Ab + (long)(128 + R1) * K + kc + C1, bb + 16384 + Y1);
    gload16(Bb + (long)R0 * K + kc + C0, bb + 32768 + Y0);
    gload16(Bb + (long)R1 * K + kc + C1, bb + 32768 + Y1);
    gload16(Bb + (long)(128 + R0) * K + kc + C0, bb + 49152 + Y0);
    gload16(Bb + (long)(128 + R1) * K + kc + C1, bb + 49152 + Y1);
  };

  f32x4 acc[8][4];
  const f32x4 fz = {0.f, 0.f, 0.f, 0.f};
#pragma unroll
  for (int mf = 0; mf < 8; ++mf)
#pragma unroll
    for (int nf = 0; nf < 4; ++nf) acc[mf][nf] = fz;

  int aoff = lr * 64 + ((lg * 16) ^ ((lr & 8) << 2));   // shared frag byte base
  int nk = K >> 6;
  stage(0, 0);
  int d = 0;
  for (int kt = 0; kt < nk; ++kt) {
    __syncthreads();                       // drains vmcnt: buf d ready for all
    if (kt + 1 < nk) stage(d ^ 1, kt + 1); // next tile's loads fly under compute
    const char* aB = smem + d * 65536 + wm * 16384;
    const char* bB = smem + d * 65536 + 32768 + (wn >> 1) * 16384;
    bf16x8 bfrag[4][2];
#pragma unroll
    for (int nf = 0; nf < 4; ++nf)
#pragma unroll
      for (int k = 0; k < 2; ++k)
        bfrag[nf][k] = *(const bf16x8*)(bB + ((((wn & 1) * 4 + nf) * 2 + k) << 10) + aoff);
#pragma unroll
    for (int p = 0; p < 4; ++p) {          // quadrant = m-frag pair
      bf16x8 af[2][2];
#pragma unroll
      for (int mi = 0; mi < 2; ++mi)
#pragma unroll
        for (int k = 0; k < 2; ++k)
          af[mi][k] = *(const bf16x8*)(aB + (((p * 2 + mi) * 2 + k) << 10) + aoff);
      __builtin_amdgcn_s_setprio(1);
#pragma unroll
      for (int mi = 0; mi < 2; ++mi)
#pragma unroll
        for (int nf = 0; nf < 4; ++nf)
#pragma unroll
          for (int k = 0; k < 2; ++k)
            acc[p * 2 + mi][nf] = __builtin_amdgcn_mfma_f32_16x16x32_bf16(
                af[mi][k], bfrag[nf][k], acc[p * 2 + mi][nf], 0, 0, 0);
      __builtin_amdgcn_s_setprio(0);
    }
    d ^= 1;
  }
  __syncthreads();   // staging done; reuse smem for C repack

  if (MODE == 0 || MODE == 1) {
    bf16* lc = (bf16*)smem;                // [256][256] bf16 = 128 KB
#pragma unroll
    for (int nf = 0; nf < 4; ++nf) {
      int col = wn * 64 + nf * 16 + lr;
      float bv = bias ? bias[boff + col0 + col] : 0.f;
#pragma unroll
      for (int mf = 0; mf < 8; ++mf) {
        int rb = wm * 128 + mf * 16 + lg * 4;
#pragma unroll
        for (int r = 0; r < 4; ++r) {
          float v = acc[mf][nf][r] + bv;
          if (MODE == 1) v = fmaxf(v, 0.f);
          lc[(rb + r) * 256 + col] = (bf16)v;
        }
      }
    }
    __syncthreads();
#pragma unroll
    for (int it = 0; it < 16; ++it) {
      int byte = it * 8192 + tid * 16;
      int rl = byte >> 9, cb = byte & 511;
      *(bf16x8*)((bf16*)outp + (row0 + rl) * N + col0 + (cb >> 1)) =
          *(const bf16x8*)(smem + byte);
    }
  } else {
#pragma unroll
    for (int h = 0; h < 2; ++h) {          // fp32: two 128-row passes
      if (h) __syncthreads();
      if (wm == h) {
        float* lf = (float*)smem;          // [128][256] f32 = 128 KB
#pragma unroll
        for (int nf = 0; nf < 4; ++nf) {
          int col = wn * 64 + nf * 16 + lr;
          float bv = bias ? bias[boff + col0 + col] : 0.f;
#pragma unroll
          for (int mf = 0; mf < 8; ++mf) {
            int rb = mf * 16 + lg * 4;
#pragma unroll
            for (int r = 0; r < 4; ++r)
              lf[(rb + r) * 256 + col] = acc[mf][nf][r] + bv;
          }
        }
      }
      __syncthreads();
#pragma unroll
      for (int it = 0; it < 16; ++it) {
        int byte = it * 8192 + tid * 16;
        int rl = byte >> 10, cb = byte & 1023;
        *(f32x4*)((float*)outp + (row0 + h * 128 + rl) * N + col0 + (cb >> 2)) =
            *(const f32x4*)(smem + byte);
      }
    }
  }
}

// ---------------- 128x128 GEMM (N=768 GEMMs), MODE 2: fp32 resid += ----------------
template <int MODE>
__global__ __launch_bounds__(256) void gemm_bt(const bf16* __restrict__ A,
    const bf16* __restrict__ Bt, const float* __restrict__ bias, long boff,
    void* __restrict__ outp, float* __restrict__ resid, int N, int K) {
  __shared__ __attribute__((aligned(16))) char smem[32768];
  int tid = threadIdx.x;
  int l = tid & 63;
  int w = tid >> 6, wr = w >> 1, wc = w & 1;
  int lg = l >> 4, lr = l & 15;

  int nwg = gridDim.x;
  int fid = blockIdx.x;
  int swz = (fid & 7) * (nwg >> 3) + (fid >> 3);
  long row0 = (long)(swz & 31) * 128;
  long col0 = (long)(swz >> 5) * 128;

  const bf16* ga = A  + (row0 + (tid >> 2)) * K + (tid & 3) * 8;
  const bf16* gb = Bt + (col0 + (tid >> 2)) * K + (tid & 3) * 8;

  f32x4 acc[4][4];
  const f32x4 fz = {0.f, 0.f, 0.f, 0.f};
#pragma unroll
  for (int m = 0; m < 4; ++m)
#pragma unroll
    for (int n = 0; n < 4; ++n) acc[m][n] = fz;

  int nk = K >> 5;
  {
    bf16* la = (bf16*)smem + tid * 8;
    bf16* lb = (bf16*)(smem + 8192) + tid * 8;
    gload16(ga, la);  gload16(ga + (long)64 * K, la + 2048);
    gload16(gb, lb);  gload16(gb + (long)64 * K, lb + 2048);
    ga += 32; gb += 32;
  }
  int cur = 0;
  for (int t = 0; t < nk; ++t) {
    __syncthreads();
    if (t + 1 < nk) {
      char* bufb = smem + (cur ^ 1) * 16384;
      bf16* la = (bf16*)bufb + tid * 8;
      bf16* lb = (bf16*)(bufb + 8192) + tid * 8;
      gload16(ga, la);  gload16(ga + (long)64 * K, la + 2048);
      gload16(gb, lb);  gload16(gb + (long)64 * K, lb + 2048);
      ga += 32; gb += 32;
    }
    const bf16* cA = (const bf16*)(smem + cur * 16384);
    const bf16* cB = (const bf16*)(smem + cur * 16384 + 8192);
    bf16x8 af[4], bfr[4];
#pragma unroll
    for (int m = 0; m < 4; ++m)
      af[m] = *(const bf16x8*)(cA + (wr * 64 + m * 16 + lr) * 32 + lg * 8);
#pragma unroll
    for (int n = 0; n < 4; ++n)
      bfr[n] = *(const bf16x8*)(cB + (wc * 64 + n * 16 + lr) * 32 + lg * 8);
#pragma unroll
    for (int m = 0; m < 4; ++m)
#pragma unroll
      for (int n = 0; n < 4; ++n)
        acc[m][n] = __builtin_amdgcn_mfma_f32_16x16x32_bf16(af[m], bfr[n], acc[m][n], 0, 0, 0);
    cur ^= 1;
  }
  __syncthreads();

#pragma unroll
  for (int pair = 0; pair < 2; ++pair) {
    float* lcf = (float*)smem;
#pragma unroll
    for (int n = 0; n < 4; ++n) {
      int gcl = wc * 64 + n * 16 + lr;
      float bv = bias ? bias[boff + col0 + gcl] : 0.f;
#pragma unroll
      for (int mi = 0; mi < 2; ++mi) {
        int m = pair * 2 + mi;
        int rl = wr * 32 + mi * 16 + lg * 4;
#pragma unroll
        for (int r = 0; r < 4; ++r)
          lcf[(rl + r) * 128 + gcl] = acc[m][n][r] + bv;
      }
    }
    __syncthreads();
#pragma unroll
    for (int it = 0; it < 8; ++it) {
      int byte = it * 4096 + tid * 16;
      int rl = byte >> 9;
      int cb = byte & 511;
      long gr = row0 + (rl >> 5) * 64 + pair * 32 + ((rl >> 4) & 1) * 16 + (rl & 15);
      f32x4 v = *(const f32x4*)(smem + byte);
      if (MODE == 2) {
        f32x4 g = *(const f32x4*)(resid + gr * N + col0 + (cb >> 2));
        v += g;
        *(f32x4*)(resid + gr * N + col0 + (cb >> 2)) = v;
      } else {
        *(f32x4*)((float*)outp + gr * N + col0 + (cb >> 2)) = v;
      }
    }
    __syncthreads();
  }
}

// ---------------- flash attention ----------------
#define TRRD(D, OFF) asm volatile("ds_read_b64_tr_b16 %0, %1 offset:" OFF \
                                  : "=v"(D) : "v"(trp))
__global__ __launch_bounds__(64) void attn_kernel(const bf16* __restrict__ qkv,
                                                  bf16* __restrict__ attout) {
  int fid = blockIdx.x;
  int swzb = (fid & 7) * 384 + (fid >> 3);
  int qt = swzb & 63;
  int bh = swzb >> 6;
  int b = bh / C_H, h = bh % C_H;
  int l = threadIdx.x;
  int lg = l >> 4, lr = l & 15;
  const bf16* base = qkv + (long)b * C_T * QKVN;

  const bf16* qp = base + (long)(qt * 16 + lr) * QKVN + h * C_HS;
  bf16x8 qf0 = *(const bf16x8*)(qp + lg * 8);
  bf16x8 qf1 = *(const bf16x8*)(qp + 32 + lg * 8);

  const f32x4 fz = {0.f, 0.f, 0.f, 0.f};
  f32x4 o[4] = {fz, fz, fz, fz};
  float m_run[4], l_run[4];
#pragma unroll
  for (int r = 0; r < 4; ++r) { m_run[r] = -1e30f; l_run[r] = 0.f; }

  __shared__ __attribute__((aligned(16))) bf16 p_lds[16][40];
  __shared__ __attribute__((aligned(16))) bf16 vt_sub[2048];

  unsigned trp = (unsigned)(unsigned long)
      ((const __attribute__((address_space(3))) char*)vt_sub + l * 8);

  int nkt = (qt * 16 + 15) / 32 + 1;
  for (int kt = 0; kt < nkt; ++kt) {
    int key0 = kt * 32;
    f32x4 sacc[2];
#pragma unroll
    for (int ss = 0; ss < 2; ++ss) {
      const bf16* kp = base + (long)(key0 + ss * 16 + lr) * QKVN + C_D + h * C_HS;
      bf16x8 kf0 = *(const bf16x8*)(kp + lg * 8);
      bf16x8 kf1 = *(const bf16x8*)(kp + 32 + lg * 8);
      f32x4 a = fz;
      a = __builtin_amdgcn_mfma_f32_16x16x32_bf16(qf0, kf0, a, 0, 0, 0);
      a = __builtin_amdgcn_mfma_f32_16x16x32_bf16(qf1, kf1, a, 0, 0, 0);
      sacc[ss] = a;
    }
#pragma unroll
    for (int r = 0; r < 4; ++r) {
      int qrow = qt * 16 + lg * 4 + r;
      bool u0 = (key0 + lr) <= qrow;
      bool u1 = (key0 + 16 + lr) <= qrow;
      float s0 = u0 ? sacc[0][r] * 0.125f : -1e30f;
      float s1 = u1 ? sacc[1][r] * 0.125f : -1e30f;
      float mr = fmaxf(s0, s1);
      mr = fmaxf(mr, __shfl_xor(mr, 1));
      mr = fmaxf(mr, __shfl_xor(mr, 2));
      mr = fmaxf(mr, __shfl_xor(mr, 4));
      mr = fmaxf(mr, __shfl_xor(mr, 8));
      float mnew = fmaxf(m_run[r], mr);
      float scale = __expf(m_run[r] - mnew);
      float p0 = u0 ? __expf(s0 - mnew) : 0.f;
      float p1 = u1 ? __expf(s1 - mnew) : 0.f;
      float rs = p0 + p1;
      rs += __shfl_xor(rs, 1);
      rs += __shfl_xor(rs, 2);
      rs += __shfl_xor(rs, 4);
      rs += __shfl_xor(rs, 8);
      l_run[r] = l_run[r] * scale + rs;
      m_run[r] = mnew;
      o[0][r] *= scale; o[1][r] *= scale; o[2][r] *= scale; o[3][r] *= scale;
      p_lds[lg * 4 + r][lr]      = (bf16)p0;
      p_lds[lg * 4 + r][16 + lr] = (bf16)p1;
    }
#pragma unroll
    for (int it = 0; it < 4; ++it) {
      int kl = it * 8 + (l >> 3);
      int d0 = (l & 7) * 8;
      bf16x8 vv = *(const bf16x8*)(base + (long)(key0 + kl) * QKVN + 2 * C_D + h * C_HS + d0);
      int ba = ((d0 >> 4) << 10) + (((kl >> 2) & 1) << 9) + ((kl >> 3) << 7)
             + ((kl & 3) << 5) + ((d0 & 15) << 1);
      *(bf16x8*)((char*)vt_sub + ba) = vv;
    }
    __syncthreads();
    s16x4 t0a, t0b, t1a, t1b, t2a, t2b, t3a, t3b;
    TRRD(t0a, "0");    TRRD(t0b, "512");
    TRRD(t1a, "1024"); TRRD(t1b, "1536");
    TRRD(t2a, "2048"); TRRD(t2b, "2560");
    TRRD(t3a, "3072"); TRRD(t3b, "3584");
    bf16x8 pf = *(const bf16x8*)(&p_lds[lr][lg * 8]);
    asm volatile("s_waitcnt lgkmcnt(0)" ::: "memory");
    __builtin_amdgcn_sched_barrier(0);
    union uu { short s[8]; bf16x8 v; };
    auto mk = [](s16x4 a, s16x4 bq) {
      uu u;
      u.s[0] = a[0]; u.s[1] = a[1]; u.s[2] = a[2]; u.s[3] = a[3];
      u.s[4] = bq[0]; u.s[5] = bq[1]; u.s[6] = bq[2]; u.s[7] = bq[3];
      return u.v;
    };
    o[0] = __builtin_amdgcn_mfma_f32_16x16x32_bf16(pf, mk(t0a, t0b), o[0], 0, 0, 0);
    o[1] = __builtin_amdgcn_mfma_f32_16x16x32_bf16(pf, mk(t1a, t1b), o[1], 0, 0, 0);
    o[2] = __builtin_amdgcn_mfma_f32_16x16x32_bf16(pf, mk(t2a, t2b), o[2], 0, 0, 0);
    o[3] = __builtin_amdgcn_mfma_f32_16x16x32_bf16(pf, mk(t3a, t3b), o[3], 0, 0, 0);
    __syncthreads();
  }
#pragma unroll
  for (int c = 0; c < 4; ++c)
#pragma unroll
    for (int r = 0; r < 4; ++r) {
      int qrow = qt * 16 + lg * 4 + r;
      attout[((long)b * C_T + qrow) * C_D + h * C_HS + c * 16 + lr] =
          (bf16)(o[c][r] / l_run[r]);
    }
}

// ---------------- loss ----------------
__global__ __launch_bounds__(256) void loss_kernel(const float* __restrict__ logits,
    const int* __restrict__ targets, float* __restrict__ rowloss) {
  int row = blockIdx.x, tid = threadIdx.x;
  const float* lrow = logits + (long)row * C_V;
  float m = -1e30f, sum = 0.f;
  for (int i4 = tid * 4; i4 < C_V; i4 += 1024) {
    f32x4 v4 = *(const f32x4*)(lrow + i4);
#pragma unroll
    for (int j = 0; j < 4; ++j) {
      float v = v4[j];
      if (v > m) { sum *= __expf(m - v); m = v; }
      sum += __expf(v - m);
    }
  }
#pragma unroll
  for (int off = 32; off > 0; off >>= 1) {
    float mo = __shfl_down(m, off), so = __shfl_down(sum, off);
    float M = fmaxf(m, mo);
    sum = sum * __expf(m - M) + so * __expf(mo - M);
    m = M;
  }
  __shared__ float sm[4], ss[4];
  if ((tid & 63) == 0) { sm[tid >> 6] = m; ss[tid >> 6] = sum; }
  __syncthreads();
  if (tid == 0) {
    float M = sm[0], S = ss[0];
    for (int wv = 1; wv < 4; ++wv) {
      float M2 = fmaxf(M, sm[wv]);
      S = S * __expf(M - M2) + ss[wv] * __expf(sm[wv] - M2);
      M = M2;
    }
    float lt = lrow[targets[row]];
    rowloss[row] = -(lt - M - logf(S));
  }
}

__global__ __launch_bounds__(256) void loss_final(const float* __restrict__ rowloss,
                                                  float* __restrict__ out) {
  int tid = threadIdx.x;
  float s = 0.f;
  for (int i = tid; i < ROWS; i += 256) s += rowloss[i];
#pragma unroll
  for (int off = 32; off > 0; off >>= 1) s += __shfl_down(s, off);
  __shared__ float sm[4];
  if ((tid & 63) == 0) sm[tid >> 6] = s;
  __syncthreads();
  if (tid == 0) out[0] = (sm[0] + sm[1] + sm[2] + sm[3]) * (1.f / ROWS);
}

// ---------------- launch ----------------
extern "C" void kernel_launch(void* const* d_in, const int* in_sizes, int n_in,
                              void* d_out, int out_size, void* d_ws, size_t ws_size,
                              hipStream_t stream) {
  (void)in_sizes; (void)n_in; (void)out_size; (void)ws_size;
  const int*   idx     = (const int*)  d_in[0];
  const int*   targets = (const int*)  d_in[1];
  const float* tok     = (const float*)d_in[2];
  const float* pos     = (const float*)d_in[3];
  const float* Wq      = (const float*)d_in[4];
  const float* Wk      = (const float*)d_in[5];
  const float* Wv      = (const float*)d_in[6];
  const float* Wo      = (const float*)d_in[7];
  const float* bo      = (const float*)d_in[8];
  const float* W1      = (const float*)d_in[9];
  const float* b1      = (const float*)d_in[10];
  const float* W2      = (const float*)d_in[11];
  const float* b2      = (const float*)d_in[12];
  const float* ln1g    = (const float*)d_in[13];
  const float* ln1b    = (const float*)d_in[14];
  const float* ln2g    = (const float*)d_in[15];
  const float* ln2b    = (const float*)d_in[16];
  const float* lnfg    = (const float*)d_in[17];
  const float* lnfb    = (const float*)d_in[18];
  const float* Wlm     = (const float*)d_in[19];
  const float* blm     = (const float*)d_in[20];

  char* p = (char*)d_ws;
  auto alloc = [&](size_t bytes) {
    char* r = p; p += (bytes + 255) & ~(size_t)255; return r;
  };
  float* x       = (float*)alloc((size_t)ROWS * C_D * 4);
  bf16*  h       = (bf16*) alloc((size_t)ROWS * C_D * 2);
  bf16*  qkv     = (bf16*) alloc((size_t)ROWS * QKVN * 2);
  bf16*  attout  = (bf16*) alloc((size_t)ROWS * C_D * 2);
  bf16*  ffbuf   = (bf16*) alloc((size_t)ROWS * C_FF * 2);
  bf16*  wqkvt   = (bf16*) alloc((size_t)QKVN * C_D * 2);
  bf16*  wot     = (bf16*) alloc((size_t)C_D * C_D * 2);
  bf16*  w1t     = (bf16*) alloc((size_t)C_FF * C_D * 2);
  bf16*  w2t     = (bf16*) alloc((size_t)C_D * C_FF * 2);
  float* rowloss = (float*)alloc((size_t)ROWS * 4);
  bf16*  wlmt    = qkv;   // alias after layer loop

  float* logits = (float*)d_out;

  embed_kernel<<<ROWS * C_D / 256, 256, 0, stream>>>(idx, tok, pos, x);

  for (int l = 0; l < C_L; ++l) {
    transpose_layer_kernel<<<6912, 256, 0, stream>>>(
        Wq, Wk, Wv, Wo, W1, W2, wqkvt, wot, w1t, w2t, l);

    ln_kernel<<<ROWS, 256, 0, stream>>>(x, ln1g, ln1b, (long)l * C_D, h);
    gemm256<0><<<16 * (QKVN / 256), 512, 0, stream>>>(
        h, wqkvt, nullptr, 0, qkv, QKVN, C_D);
    attn_kernel<<<C_B * C_H * (C_T / 16), 64, 0, stream>>>(qkv, attout);
    gemm_bt<2><<<(C_D / 128) * 32, 256, 0, stream>>>(
        attout, wot, bo, (long)l * C_D, nullptr, x, C_D, C_D);
    ln_kernel<<<ROWS, 256, 0, stream>>>(x, ln2g, ln2b, (long)l * C_D, h);
    gemm256<1><<<16 * (C_FF / 256), 512, 0, stream>>>(
        h, w1t, b1, (long)l * C_FF, ffbuf, C_FF, C_D);
    gemm_bt<2><<<(C_D / 128) * 32, 256, 0, stream>>>(
        ffbuf, w2t, b2, (long)l * C_D, nullptr, x, C_D, C_FF);
  }

  transpose_kernel<<<(C_V / 32) * (C_D / 32), 256, 0, stream>>>(
      Wlm, wlmt, C_D, C_V, 0, C_V / 32);

  ln_kernel<<<ROWS, 256, 0, stream>>>(x, lnfg, lnfb, 0, h);
  gemm256<3><<<16 * (C_V / 256), 512, 0, stream>>>(
      h, wlmt, blm, 0, logits, C_V, C_D);
  loss_kernel<<<ROWS, 256, 0, stream>>>(logits, targets, rowloss);
  loss_final<<<1, 256, 0, stream>>>(rowloss, logits + (long)ROWS * C_V);
}